// Round 11
// baseline (1176.847 us; speedup 1.0000x reference)
//
#include <hip/hip_runtime.h>
#include <hip/hip_bf16.h>
#include <cstddef>

#define N_NODES 100000
#define N_EDGES 3200000
#define N_GRAPHS 2048
#define IN_FEATS 64
#define HIDDEN 128
#define EXTRA 8

#define SCAN_CHUNK 1024
#define NB_CHUNKS ((N_NODES + SCAN_CHUNK - 1) / SCAN_CHUNK)  // 98

// counting-sort parameters: u8x4-packed LDS bins, 64000 bins/pass, 2 passes
#define R_BINS 64000
#define NPASS 2                      // 2 * 64000 >= 100000
#define G_SORT 256
#define CHUNK (N_EDGES / G_SORT)     // 12500

typedef unsigned short bf16_t;
typedef short bfx8 __attribute__((ext_vector_type(8)));
typedef float f32x4 __attribute__((ext_vector_type(4)));

__device__ __forceinline__ float selu_f(float x) {
    const float scale = 1.0507009873554805f;
    const float alpha = 1.6732632423543772f;
    return x > 0.f ? scale * x : scale * alpha * (__expf(x) - 1.f);
}
__device__ __forceinline__ float bf2f(unsigned short u) {
    union { unsigned int i; float f; } c; c.i = ((unsigned int)u) << 16; return c.f;
}
__device__ __forceinline__ unsigned short f2bf(float f) {
    union { float f; unsigned int i; } c; c.f = f;
    unsigned int lsb = (c.i >> 16) & 1;
    c.i += 0x7fffu + lsb;                 // round to nearest even
    return (unsigned short)(c.i >> 16);
}

// ============ counting-sort CSR build (no global atomics) ============

__global__ __launch_bounds__(512) void histo_kernel(const int* __restrict__ src,
                                                    const int* __restrict__ dst,
                                                    unsigned char* __restrict__ h_src,
                                                    unsigned char* __restrict__ h_dst) {
    __shared__ unsigned int hist[R_BINS / 4];   // 16000 words, 64000 B
    const int b = blockIdx.x, t = threadIdx.x;
    const int e0 = b * CHUNK;
#pragma unroll
    for (int ph = 0; ph < 2; ++ph) {
        const int4* key4 = (const int4*)((ph ? src : dst) + e0);
        unsigned char* hout = (ph ? h_src : h_dst) + (size_t)b * N_NODES;
        for (int p = 0; p < NPASS; ++p) {
            const int r0 = p * R_BINS;
            const int rend = min(R_BINS, N_NODES - r0);   // 64000 / 36000
            for (int i = t; i < R_BINS / 4; i += 512) hist[i] = 0;
            __syncthreads();
            for (int i = t; i < CHUNK / 4; i += 512) {
                int4 k = key4[i];
                unsigned int x;
                x = (unsigned)(k.x - r0); if (x < (unsigned)R_BINS) atomicAdd(&hist[x >> 2], 1u << ((x & 3) << 3));
                x = (unsigned)(k.y - r0); if (x < (unsigned)R_BINS) atomicAdd(&hist[x >> 2], 1u << ((x & 3) << 3));
                x = (unsigned)(k.z - r0); if (x < (unsigned)R_BINS) atomicAdd(&hist[x >> 2], 1u << ((x & 3) << 3));
                x = (unsigned)(k.w - r0); if (x < (unsigned)R_BINS) atomicAdd(&hist[x >> 2], 1u << ((x & 3) << 3));
            }
            __syncthreads();
            unsigned int* ho4 = (unsigned int*)(hout + r0);
            for (int i = t; i < rend / 4; i += 512) ho4[i] = hist[i];
            __syncthreads();
        }
    }
}

__global__ __launch_bounds__(256) void degs_kernel(const unsigned char* __restrict__ h_src,
                                                   unsigned char* __restrict__ h_dst,
                                                   int* __restrict__ indeg,
                                                   float* __restrict__ nsrc,
                                                   float* __restrict__ ndst) {
    int bin = blockIdx.x * 256 + threadIdx.x;
    if (bin >= N_NODES) return;
    int s = 0;
#pragma unroll 8
    for (int b = 0; b < G_SORT; ++b) s += h_src[(size_t)b * N_NODES + bin];
    nsrc[bin] = rsqrtf(fmaxf((float)s, 1.f));
    int run = 0;
#pragma unroll 8
    for (int b = 0; b < G_SORT; ++b) {
        size_t off = (size_t)b * N_NODES + bin;
        int v = h_dst[off];
        h_dst[off] = (unsigned char)run;
        run += v;
    }
    indeg[bin] = run;
    ndst[bin] = rsqrtf(fmaxf((float)run, 1.f));
}

__global__ __launch_bounds__(512) void sortT_kernel(const int* __restrict__ src,
                                                    const int* __restrict__ dst,
                                                    const unsigned char* __restrict__ h_dst,
                                                    const int* __restrict__ rowptr,
                                                    int* __restrict__ csr_src) {
    __shared__ unsigned int cnt[R_BINS / 4];   // 16000 words
    const int b = blockIdx.x, t = threadIdx.x;
    const int e0 = b * CHUNK;
    const int4* d4p = (const int4*)(dst + e0);
    const int4* s4p = (const int4*)(src + e0);
    const unsigned char* hrow = h_dst + (size_t)b * N_NODES;
    for (int p = 0; p < NPASS; ++p) {
        const int r0 = p * R_BINS;
        const int rend = min(R_BINS, N_NODES - r0);
        const unsigned int* hr4 = (const unsigned int*)(hrow + r0);
        for (int i = t; i < rend / 4; i += 512) cnt[i] = hr4[i];
        __syncthreads();
        for (int i = t; i < CHUNK / 4; i += 512) {
            int4 d = d4p[i];
            int4 s = s4p[i];
            unsigned int x, old, rank;
            x = (unsigned)(d.x - r0);
            if (x < (unsigned)R_BINS) {
                old = atomicAdd(&cnt[x >> 2], 1u << ((x & 3) << 3));
                rank = (old >> ((x & 3) << 3)) & 0xffu;
                csr_src[rowptr[d.x] + rank] = s.x;
            }
            x = (unsigned)(d.y - r0);
            if (x < (unsigned)R_BINS) {
                old = atomicAdd(&cnt[x >> 2], 1u << ((x & 3) << 3));
                rank = (old >> ((x & 3) << 3)) & 0xffu;
                csr_src[rowptr[d.y] + rank] = s.y;
            }
            x = (unsigned)(d.z - r0);
            if (x < (unsigned)R_BINS) {
                old = atomicAdd(&cnt[x >> 2], 1u << ((x & 3) << 3));
                rank = (old >> ((x & 3) << 3)) & 0xffu;
                csr_src[rowptr[d.z] + rank] = s.z;
            }
            x = (unsigned)(d.w - r0);
            if (x < (unsigned)R_BINS) {
                old = atomicAdd(&cnt[x >> 2], 1u << ((x & 3) << 3));
                rank = (old >> ((x & 3) << 3)) & 0xffu;
                csr_src[rowptr[d.w] + rank] = s.w;
            }
        }
        __syncthreads();
    }
}

// ============ rowptr scan, weights, features ============

__global__ __launch_bounds__(256) void scanA(const int* __restrict__ indeg,
                                             int* __restrict__ partials) {
    __shared__ int red[4];
    const int b = blockIdx.x, t = threadIdx.x;
    int base = b * SCAN_CHUNK + t * 4;
    int s = 0;
#pragma unroll
    for (int k = 0; k < 4; ++k) { int i = base + k; if (i < N_NODES) s += indeg[i]; }
    for (int off = 32; off; off >>= 1) s += __shfl_down(s, off);
    if ((t & 63) == 0) red[t >> 6] = s;
    __syncthreads();
    if (t == 0) partials[b] = red[0] + red[1] + red[2] + red[3];
}

__global__ __launch_bounds__(128) void scanB(int* __restrict__ partials,
                                             int* __restrict__ rowptr) {
    __shared__ int s[128];
    const int t = threadIdx.x;
    int v = (t < NB_CHUNKS) ? partials[t] : 0;
    s[t] = v;
    __syncthreads();
    for (int off = 1; off < 128; off <<= 1) {
        int u = (t >= off) ? s[t - off] : 0;
        __syncthreads();
        s[t] += u;
        __syncthreads();
    }
    if (t < NB_CHUNKS) partials[t] = s[t] - v;   // exclusive
    if (t == 127) rowptr[N_NODES] = s[127];
}

__global__ __launch_bounds__(256) void scanC(const int* __restrict__ indeg,
                                             const int* __restrict__ partials,
                                             int* __restrict__ rowptr) {
    __shared__ int ts[256];
    const int b = blockIdx.x, t = threadIdx.x;
    int base = b * SCAN_CHUNK + t * 4;
    int v[4];
    int s = 0;
#pragma unroll
    for (int k = 0; k < 4; ++k) { int i = base + k; v[k] = (i < N_NODES) ? indeg[i] : 0; s += v[k]; }
    ts[t] = s;
    __syncthreads();
    for (int off = 1; off < 256; off <<= 1) {
        int u = (t >= off) ? ts[t - off] : 0;
        __syncthreads();
        ts[t] += u;
        __syncthreads();
    }
    int excl = ts[t] - s + partials[b];
#pragma unroll
    for (int k = 0; k < 4; ++k) {
        int i = base + k;
        if (i < N_NODES) rowptr[i] = excl;
        excl += v[k];
    }
}

// merged weight prep: Wt[n][k] = bf16(W[k][n]) for all three layers
__global__ __launch_bounds__(256) void wprep_kernel(const float* __restrict__ W1,
                                                    const float* __restrict__ W2,
                                                    const float* __restrict__ W3,
                                                    bf16_t* __restrict__ Wt1,
                                                    bf16_t* __restrict__ Wt2,
                                                    bf16_t* __restrict__ Wt3) {
    int i = blockIdx.x * 256 + threadIdx.x;
    if (i < 128 * IN_FEATS) {
        int n = i / IN_FEATS, k = i - n * IN_FEATS;
        Wt1[i] = f2bf(W1[k * 128 + n]);
        return;
    }
    i -= 128 * IN_FEATS;
    if (i < 128 * HIDDEN) {
        int n = i / HIDDEN, k = i - n * HIDDEN;
        Wt2[i] = f2bf(W2[k * 128 + n]);
        return;
    }
    i -= 128 * HIDDEN;
    if (i < 128 * HIDDEN) {
        int n = i / HIDDEN, k = i - n * HIDDEN;
        Wt3[i] = f2bf(W3[k * 128 + n]);
    }
}

__global__ __launch_bounds__(256) void prescale_kernel(const float* __restrict__ x,
                                                       const float* __restrict__ nsrc,
                                                       bf16_t* __restrict__ xb) {
    int i = blockIdx.x * 256 + threadIdx.x;
    const int total = N_NODES * (IN_FEATS / 4);
    if (i >= total) return;
    int node = i >> 4;                       // IN_FEATS/4 == 16
    float nm = nsrc[node];
    float4 v = ((const float4*)x)[i];
    ushort4 o;
    o.x = f2bf(v.x * nm); o.y = f2bf(v.y * nm);
    o.z = f2bf(v.z * nm); o.w = f2bf(v.w * nm);
    ((ushort4*)xb)[i] = o;
}

// ============ fused gather + MFMA matmul ============
// Block = 256 threads / 4 waves = 64 nodes. Each wave gathers its own 16
// agg rows (agg*ndst, bf16) into a swizzled LDS tile (wave-private rows ->
// no barrier between phases), then runs the 16-row MFMA tile vs sW.
// out = selu(agg_tile @ Wt + bias) [* nsrc]  -> row-major [N][128] bf16.
template <int K, bool SCALE_OUT>
__global__ __launch_bounds__(256) void gmm_kernel(const bf16_t* __restrict__ Hin,
                                                  const int* __restrict__ rowptr,
                                                  const int* __restrict__ csr_src,
                                                  const float* __restrict__ ndst,
                                                  const bf16_t* __restrict__ Wt,
                                                  const float* __restrict__ bias,
                                                  const float* __restrict__ nsrc,
                                                  bf16_t* __restrict__ outb) {
    __shared__ char sW[128 * K * 2];
    __shared__ char sT[64 * K * 2];
    const int t = threadIdx.x;

    // stage Wt [128][K] swizzled
    for (int fb = t * 16; fb < 128 * K * 2; fb += 256 * 16) {
        bfx8 v = *(const bfx8*)((const char*)Wt + fb);
        int n = fb / (2 * K);
        *(bfx8*)(sW + (fb ^ ((n & 7) << 4))) = v;
    }
    __syncthreads();

    const int wv = t >> 6;
    const int l  = t & 63;
    const int row0 = blockIdx.x * 64 + wv * 16;   // this wave's 16 nodes

    // ---- phase A: gather 16 rows into sT (wave-private) ----
    if (K == 128) {
        const int half = l >> 5;
        const int sub  = l & 31;
        for (int i = 0; i < 16; ++i) {
            const int node = row0 + i;
            float a0 = 0.f, a1 = 0.f, a2 = 0.f, a3 = 0.f;
            if (node < N_NODES) {
                const int r0 = rowptr[node], r1 = rowptr[node + 1];
                for (int base = r0; base < r1; base += 32) {
                    const int nb = min(32, r1 - base);
                    int myidx = __builtin_nontemporal_load(&csr_src[base + min(sub, nb - 1)]);
#pragma unroll 8
                    for (int j = 0; j < nb; j += 2) {
                        int e = j + half;
                        int s = __shfl(myidx, min(e, nb - 1));
                        if (e < nb) {
                            ushort4 u = *(const ushort4*)(Hin + (size_t)s * K + sub * 4);
                            a0 += bf2f(u.x); a1 += bf2f(u.y); a2 += bf2f(u.z); a3 += bf2f(u.w);
                        }
                    }
                }
            }
            a0 += __shfl_xor(a0, 32); a1 += __shfl_xor(a1, 32);
            a2 += __shfl_xor(a2, 32); a3 += __shfl_xor(a3, 32);
            if (half == 0) {
                float nm = (node < N_NODES) ? ndst[node] : 0.f;
                ushort4 o;
                o.x = f2bf(a0 * nm); o.y = f2bf(a1 * nm);
                o.z = f2bf(a2 * nm); o.w = f2bf(a3 * nm);
                int row = wv * 16 + i;
                int off = row * (2 * K) + sub * 8;
                *(ushort4*)(sT + (off ^ ((row & 7) << 4))) = o;
            }
        }
    } else {  // K == 64
        const int q   = l >> 4;
        const int s16 = l & 15;
        for (int i = 0; i < 16; ++i) {
            const int node = row0 + i;
            float a0 = 0.f, a1 = 0.f, a2 = 0.f, a3 = 0.f;
            if (node < N_NODES) {
                const int r0 = rowptr[node], r1 = rowptr[node + 1];
                for (int base = r0; base < r1; base += 16) {
                    const int nb = min(16, r1 - base);
                    int myidx = __builtin_nontemporal_load(&csr_src[base + min(s16, nb - 1)]);
#pragma unroll
                    for (int j = 0; j < 16; j += 4) {
                        if (j >= nb) break;
                        int e = j + q;
                        int s = __shfl(myidx, min(e, nb - 1));
                        if (e < nb) {
                            ushort4 u = *(const ushort4*)(Hin + (size_t)s * K + s16 * 4);
                            a0 += bf2f(u.x); a1 += bf2f(u.y); a2 += bf2f(u.z); a3 += bf2f(u.w);
                        }
                    }
                }
            }
            a0 += __shfl_xor(a0, 16); a1 += __shfl_xor(a1, 16);
            a2 += __shfl_xor(a2, 16); a3 += __shfl_xor(a3, 16);
            a0 += __shfl_xor(a0, 32); a1 += __shfl_xor(a1, 32);
            a2 += __shfl_xor(a2, 32); a3 += __shfl_xor(a3, 32);
            if (q == 0) {
                float nm = (node < N_NODES) ? ndst[node] : 0.f;
                ushort4 o;
                o.x = f2bf(a0 * nm); o.y = f2bf(a1 * nm);
                o.z = f2bf(a2 * nm); o.w = f2bf(a3 * nm);
                int row = wv * 16 + i;
                int off = row * (2 * K) + s16 * 8;
                *(ushort4*)(sT + (off ^ ((row & 7) << 4))) = o;
            }
        }
    }

    // ---- phase B: 16-row MFMA tile from sT (same wave's rows) ----
    const int m  = l & 15;
    const int kb = l >> 4;

    f32x4 acc[8];
#pragma unroll
    for (int f = 0; f < 8; ++f) acc[f] = (f32x4){0.f, 0.f, 0.f, 0.f};

#pragma unroll
    for (int kc = 0; kc < K / 32; ++kc) {
        int arow = wv * 16 + m;
        int aoff = arow * (2 * K) + kc * 64 + kb * 16;
        aoff ^= (arow & 7) << 4;
        bfx8 a = *(const bfx8*)(sT + aoff);
#pragma unroll
        for (int f = 0; f < 8; ++f) {
            int n = f * 16 + m;
            int off = n * (2 * K) + kc * 64 + kb * 16;
            off ^= (n & 7) << 4;
            bfx8 b = *(const bfx8*)(sW + off);
            acc[f] = __builtin_amdgcn_mfma_f32_16x16x32_bf16(a, b, acc[f], 0, 0, 0);
        }
    }

    int nodes[4];
    float nm[4];
#pragma unroll
    for (int j = 0; j < 4; ++j) {
        nodes[j] = row0 + kb * 4 + j;
        nm[j] = 1.f;
        if (SCALE_OUT && nodes[j] < N_NODES) nm[j] = nsrc[nodes[j]];
    }
#pragma unroll
    for (int f = 0; f < 8; ++f) {
        int feat = f * 16 + m;
        float bb = bias[feat];
#pragma unroll
        for (int j = 0; j < 4; ++j) {
            if (nodes[j] < N_NODES) {
                float v = selu_f(acc[f][j] + bb) * nm[j];
                outb[(size_t)nodes[j] * HIDDEN + feat] = f2bf(v);
            }
        }
    }
}

// ============ pool + MLP head ============
__global__ __launch_bounds__(256) void pool_kernel(const bf16_t* __restrict__ h,
                                                   const int* __restrict__ gid,
                                                   float* __restrict__ emb,
                                                   float* __restrict__ cnt) {
    const int lane = threadIdx.x & 63;
    const int wid = (blockIdx.x * 256 + threadIdx.x) >> 6;
    const int n0 = wid * 64;
    if (n0 >= N_NODES) return;
    const int nend = (n0 + 64 < N_NODES) ? n0 + 64 : N_NODES;
    int cur = gid[n0];
    float ax = 0.f, ay = 0.f, run = 0.f;
    for (int n = n0; n < nend; ++n) {
        int g = gid[n];
        if (g != cur) {
            atomicAdd(&emb[(size_t)cur * HIDDEN + lane * 2], ax);
            atomicAdd(&emb[(size_t)cur * HIDDEN + lane * 2 + 1], ay);
            if (lane == 0) atomicAdd(&cnt[cur], run);
            cur = g; ax = 0.f; ay = 0.f; run = 0.f;
        }
        ushort2 u = *(const ushort2*)(h + (size_t)n * HIDDEN + lane * 2);
        ax += bf2f(u.x); ay += bf2f(u.y);
        run += 1.f;
    }
    atomicAdd(&emb[(size_t)cur * HIDDEN + lane * 2], ax);
    atomicAdd(&emb[(size_t)cur * HIDDEN + lane * 2 + 1], ay);
    if (lane == 0) atomicAdd(&cnt[cur], run);
}

__global__ __launch_bounds__(256) void mlp_kernel(const float* __restrict__ emb,
                                                  const float* __restrict__ cnt,
                                                  const float* __restrict__ fg,
                                                  const float* __restrict__ M1, const float* __restrict__ c1,
                                                  const float* __restrict__ M2, const float* __restrict__ c2,
                                                  const float* __restrict__ M3, const float* __restrict__ c3,
                                                  float* __restrict__ out) {
    const int g = blockIdx.x;
    const int t = threadIdx.x;
    __shared__ float z[HIDDEN + EXTRA];
    __shared__ float z1[2 * HIDDEN];
    __shared__ float z2[HIDDEN];
    if (t < HIDDEN) {
        float c = fmaxf(cnt[g], 1.f);
        z[t] = emb[(size_t)g * HIDDEN + t] / c;
    } else if (t < HIDDEN + EXTRA) {
        z[t] = fg[g * EXTRA + (t - HIDDEN)];
    }
    __syncthreads();
    {
        float s = c1[t];
        for (int k = 0; k < HIDDEN + EXTRA; ++k) s += z[k] * M1[k * (2 * HIDDEN) + t];
        z1[t] = selu_f(s);
    }
    __syncthreads();
    if (t < HIDDEN) {
        float s = c2[t];
        for (int k = 0; k < 2 * HIDDEN; ++k) s += z1[k] * M2[k * HIDDEN + t];
        z2[t] = selu_f(s);
    }
    __syncthreads();
    if (t < 64) {
        float s = z2[t] * M3[t] + z2[t + 64] * M3[t + 64];
#pragma unroll
        for (int off = 32; off; off >>= 1) s += __shfl_down(s, off);
        if (t == 0) out[g] = s + c3[0];
    }
}

extern "C" void kernel_launch(void* const* d_in, const int* in_sizes, int n_in,
                              void* d_out, int out_size, void* d_ws, size_t ws_size,
                              hipStream_t stream) {
    const float* feats_node  = (const float*)d_in[0];
    const float* feats_graph = (const float*)d_in[1];
    const int*   src         = (const int*)d_in[2];
    const int*   dst         = (const int*)d_in[3];
    const int*   gid         = (const int*)d_in[4];
    const float* W1 = (const float*)d_in[5];
    const float* b1 = (const float*)d_in[6];
    const float* W2 = (const float*)d_in[7];
    const float* b2 = (const float*)d_in[8];
    const float* W3 = (const float*)d_in[9];
    const float* b3 = (const float*)d_in[10];
    const float* M1 = (const float*)d_in[11];
    const float* c1 = (const float*)d_in[12];
    const float* M2 = (const float*)d_in[13];
    const float* c2 = (const float*)d_in[14];
    const float* M3 = (const float*)d_in[15];
    const float* c3 = (const float*)d_in[16];
    float* out = (float*)d_out;

    char* ws = (char*)d_ws;
    int* indeg   = (int*)ws;  ws += (size_t)N_NODES * sizeof(int);
    int* rowptr  = (int*)ws;  ws += (size_t)(N_NODES + 4) * sizeof(int);
    int* partials= (int*)ws;  ws += 128 * sizeof(int);
    float* norm_src = (float*)ws; ws += (size_t)N_NODES * sizeof(float);
    float* norm_dst = (float*)ws; ws += (size_t)N_NODES * sizeof(float);
    bf16_t* Wt1 = (bf16_t*)ws; ws += (size_t)128 * IN_FEATS * sizeof(bf16_t);
    bf16_t* Wt2 = (bf16_t*)ws; ws += (size_t)128 * HIDDEN * sizeof(bf16_t);
    bf16_t* Wt3 = (bf16_t*)ws; ws += (size_t)128 * HIDDEN * sizeof(bf16_t);
    int* csr_src = (int*)ws;  ws += (size_t)N_EDGES * sizeof(int);
    bf16_t* bufB = (bf16_t*)ws; ws += (size_t)N_NODES * HIDDEN * sizeof(bf16_t);
    // union 1: h_dst (alive histo..sortT) / bufA (alive after sortT)
    unsigned char* h_dst = (unsigned char*)ws;
    bf16_t* bufA = (bf16_t*)ws;
    ws += (size_t)G_SORT * N_NODES;                                  // 25.6 MB
    // union 2: h_src (alive histo..degs) / xb + emb + cnt
    unsigned char* h_src = (unsigned char*)ws;
    bf16_t* xb   = (bf16_t*)ws;
    float* emb   = (float*)(ws + (size_t)N_NODES * IN_FEATS * sizeof(bf16_t));
    float* cnt   = emb + (size_t)N_GRAPHS * HIDDEN;
    ws += (size_t)G_SORT * N_NODES;                                  // 25.6 MB

    // ---- CSR build (counting sort, no global atomics) ----
    histo_kernel<<<G_SORT, 512, 0, stream>>>(src, dst, h_src, h_dst);
    degs_kernel<<<(N_NODES + 255) / 256, 256, 0, stream>>>(h_src, h_dst, indeg, norm_src, norm_dst);
    scanA<<<NB_CHUNKS, 256, 0, stream>>>(indeg, partials);
    scanB<<<1, 128, 0, stream>>>(partials, rowptr);
    scanC<<<NB_CHUNKS, 256, 0, stream>>>(indeg, partials, rowptr);
    sortT_kernel<<<G_SORT, 512, 0, stream>>>(src, dst, h_dst, rowptr, csr_src);

    // ---- weight prep + prescale (xb overlays h_src: dead after degs) ----
    const int wtot = 128 * IN_FEATS + 2 * 128 * HIDDEN;
    wprep_kernel<<<(wtot + 255) / 256, 256, 0, stream>>>(W1, W2, W3, Wt1, Wt2, Wt3);
    prescale_kernel<<<(N_NODES * (IN_FEATS / 4) + 255) / 256, 256, 0, stream>>>(feats_node, norm_src, xb);

    const int gmm_grid = (N_NODES + 63) / 64;

    // layer 1: fused gather(64) + MFMA(64->128) + selu/bias/nsrc epilogue
    gmm_kernel<IN_FEATS, true><<<gmm_grid, 256, 0, stream>>>(xb, rowptr, csr_src, norm_dst, Wt1, b1, norm_src, bufB);
    // layer 2
    gmm_kernel<HIDDEN, true><<<gmm_grid, 256, 0, stream>>>(bufB, rowptr, csr_src, norm_dst, Wt2, b2, norm_src, bufA);
    // layer 3 (no nsrc on output; feeds pooling)
    gmm_kernel<HIDDEN, false><<<gmm_grid, 256, 0, stream>>>(bufA, rowptr, csr_src, norm_dst, Wt3, b3, norm_src, bufB);

    // readout + MLP (emb/cnt overlay xb tail region; xb dead after layer 1)
    hipMemsetAsync(emb, 0, ((size_t)N_GRAPHS * HIDDEN + N_GRAPHS) * sizeof(float), stream);
    const int n_waves = (N_NODES + 63) / 64;
    pool_kernel<<<(n_waves + 3) / 4, 256, 0, stream>>>(bufB, gid, emb, cnt);
    mlp_kernel<<<N_GRAPHS, 256, 0, stream>>>(emb, cnt, feats_graph,
                                             M1, c1, M2, c2, M3, c3, out);
}

// Round 12
// 1033.866 us; speedup vs baseline: 1.1383x; 1.1383x over previous
//
#include <hip/hip_runtime.h>
#include <hip/hip_bf16.h>
#include <cstddef>

#define N_NODES 100000
#define N_EDGES 3200000
#define N_GRAPHS 2048
#define IN_FEATS 64
#define HIDDEN 128
#define EXTRA 8

#define SCAN_CHUNK 256
#define NB_CHUNKS ((N_NODES + SCAN_CHUNK - 1) / SCAN_CHUNK)  // 391

// counting-sort parameters: u8x4-packed LDS bins, 64000 bins/pass, 2 passes
#define R_BINS 64000
#define NPASS 2                      // 2 * 64000 >= 100000
#define G_SORT 256
#define CHUNK (N_EDGES / G_SORT)     // 12500

typedef unsigned short bf16_t;
typedef short bfx8 __attribute__((ext_vector_type(8)));
typedef float f32x4 __attribute__((ext_vector_type(4)));

__device__ __forceinline__ float selu_f(float x) {
    const float scale = 1.0507009873554805f;
    const float alpha = 1.6732632423543772f;
    return x > 0.f ? scale * x : scale * alpha * (__expf(x) - 1.f);
}
__device__ __forceinline__ float bf2f(unsigned short u) {
    union { unsigned int i; float f; } c; c.i = ((unsigned int)u) << 16; return c.f;
}
__device__ __forceinline__ unsigned short f2bf(float f) {
    union { float f; unsigned int i; } c; c.f = f;
    unsigned int lsb = (c.i >> 16) & 1;
    c.i += 0x7fffu + lsb;                 // round to nearest even
    return (unsigned short)(c.i >> 16);
}

// ============ counting-sort CSR build (no global atomics) ============

__global__ __launch_bounds__(512) void histo_kernel(const int* __restrict__ src,
                                                    const int* __restrict__ dst,
                                                    unsigned char* __restrict__ h_src,
                                                    unsigned char* __restrict__ h_dst) {
    __shared__ unsigned int hist[R_BINS / 4];   // 16000 words, 64000 B
    const int b = blockIdx.x, t = threadIdx.x;
    const int e0 = b * CHUNK;
#pragma unroll
    for (int ph = 0; ph < 2; ++ph) {
        const int4* key4 = (const int4*)((ph ? src : dst) + e0);
        unsigned char* hout = (ph ? h_src : h_dst) + (size_t)b * N_NODES;
        for (int p = 0; p < NPASS; ++p) {
            const int r0 = p * R_BINS;
            const int rend = min(R_BINS, N_NODES - r0);   // 64000 / 36000
            for (int i = t; i < R_BINS / 4; i += 512) hist[i] = 0;
            __syncthreads();
            for (int i = t; i < CHUNK / 4; i += 512) {
                int4 k = key4[i];
                unsigned int x;
                x = (unsigned)(k.x - r0); if (x < (unsigned)R_BINS) atomicAdd(&hist[x >> 2], 1u << ((x & 3) << 3));
                x = (unsigned)(k.y - r0); if (x < (unsigned)R_BINS) atomicAdd(&hist[x >> 2], 1u << ((x & 3) << 3));
                x = (unsigned)(k.z - r0); if (x < (unsigned)R_BINS) atomicAdd(&hist[x >> 2], 1u << ((x & 3) << 3));
                x = (unsigned)(k.w - r0); if (x < (unsigned)R_BINS) atomicAdd(&hist[x >> 2], 1u << ((x & 3) << 3));
            }
            __syncthreads();
            unsigned int* ho4 = (unsigned int*)(hout + r0);
            for (int i = t; i < rend / 4; i += 512) ho4[i] = hist[i];
            __syncthreads();
        }
    }
}

// merged: nsrc from colsum(h_src); h_dst -> in-place per-bin block prefix;
// indeg/ndst; block partial sums of indeg -> partials (scanA folded in)
__global__ __launch_bounds__(256) void degs_kernel(const unsigned char* __restrict__ h_src,
                                                   unsigned char* __restrict__ h_dst,
                                                   int* __restrict__ indeg,
                                                   float* __restrict__ nsrc,
                                                   float* __restrict__ ndst,
                                                   int* __restrict__ partials) {
    __shared__ int red[4];
    const int bin = blockIdx.x * 256 + threadIdx.x;
    int run = 0;
    if (bin < N_NODES) {
        int s = 0;
#pragma unroll 8
        for (int b = 0; b < G_SORT; ++b) s += h_src[(size_t)b * N_NODES + bin];
        nsrc[bin] = rsqrtf(fmaxf((float)s, 1.f));
#pragma unroll 8
        for (int b = 0; b < G_SORT; ++b) {
            size_t off = (size_t)b * N_NODES + bin;
            int v = h_dst[off];
            h_dst[off] = (unsigned char)run;
            run += v;
        }
        indeg[bin] = run;
        ndst[bin] = rsqrtf(fmaxf((float)run, 1.f));
    }
    int sum = run;
    for (int off = 32; off; off >>= 1) sum += __shfl_down(sum, off);
    if ((threadIdx.x & 63) == 0) red[threadIdx.x >> 6] = sum;
    __syncthreads();
    if (threadIdx.x == 0) partials[blockIdx.x] = red[0] + red[1] + red[2] + red[3];
}

__global__ __launch_bounds__(512) void sortT_kernel(const int* __restrict__ src,
                                                    const int* __restrict__ dst,
                                                    const unsigned char* __restrict__ h_dst,
                                                    const int* __restrict__ rowptr,
                                                    int* __restrict__ csr_src) {
    __shared__ unsigned int cnt[R_BINS / 4];   // 16000 words
    const int b = blockIdx.x, t = threadIdx.x;
    const int e0 = b * CHUNK;
    const int4* d4p = (const int4*)(dst + e0);
    const int4* s4p = (const int4*)(src + e0);
    const unsigned char* hrow = h_dst + (size_t)b * N_NODES;
    for (int p = 0; p < NPASS; ++p) {
        const int r0 = p * R_BINS;
        const int rend = min(R_BINS, N_NODES - r0);
        const unsigned int* hr4 = (const unsigned int*)(hrow + r0);
        for (int i = t; i < rend / 4; i += 512) cnt[i] = hr4[i];
        __syncthreads();
        for (int i = t; i < CHUNK / 4; i += 512) {
            int4 d = d4p[i];
            int4 s = s4p[i];
            unsigned int x, old, rank;
            x = (unsigned)(d.x - r0);
            if (x < (unsigned)R_BINS) {
                old = atomicAdd(&cnt[x >> 2], 1u << ((x & 3) << 3));
                rank = (old >> ((x & 3) << 3)) & 0xffu;
                csr_src[rowptr[d.x] + rank] = s.x;
            }
            x = (unsigned)(d.y - r0);
            if (x < (unsigned)R_BINS) {
                old = atomicAdd(&cnt[x >> 2], 1u << ((x & 3) << 3));
                rank = (old >> ((x & 3) << 3)) & 0xffu;
                csr_src[rowptr[d.y] + rank] = s.y;
            }
            x = (unsigned)(d.z - r0);
            if (x < (unsigned)R_BINS) {
                old = atomicAdd(&cnt[x >> 2], 1u << ((x & 3) << 3));
                rank = (old >> ((x & 3) << 3)) & 0xffu;
                csr_src[rowptr[d.z] + rank] = s.z;
            }
            x = (unsigned)(d.w - r0);
            if (x < (unsigned)R_BINS) {
                old = atomicAdd(&cnt[x >> 2], 1u << ((x & 3) << 3));
                rank = (old >> ((x & 3) << 3)) & 0xffu;
                csr_src[rowptr[d.w] + rank] = s.w;
            }
        }
        __syncthreads();
    }
}

// ============ rowptr scan ============

__global__ __launch_bounds__(512) void scanB(int* __restrict__ partials,
                                             int* __restrict__ rowptr) {
    __shared__ int s[512];
    const int t = threadIdx.x;
    int v = (t < NB_CHUNKS) ? partials[t] : 0;
    s[t] = v;
    __syncthreads();
    for (int off = 1; off < 512; off <<= 1) {
        int u = (t >= off) ? s[t - off] : 0;
        __syncthreads();
        s[t] += u;
        __syncthreads();
    }
    if (t < NB_CHUNKS) partials[t] = s[t] - v;   // exclusive
    if (t == 511) rowptr[N_NODES] = s[511];
}

__global__ __launch_bounds__(256) void scanC(const int* __restrict__ indeg,
                                             const int* __restrict__ partials,
                                             int* __restrict__ rowptr) {
    __shared__ int ts[256];
    const int b = blockIdx.x, t = threadIdx.x;
    const int i = b * 256 + t;
    int v = (i < N_NODES) ? indeg[i] : 0;
    ts[t] = v;
    __syncthreads();
    for (int off = 1; off < 256; off <<= 1) {
        int u = (t >= off) ? ts[t - off] : 0;
        __syncthreads();
        ts[t] += u;
        __syncthreads();
    }
    int excl = ts[t] - v + partials[b];
    if (i < N_NODES) rowptr[i] = excl;
}

// merged weight prep: Wt[n][k] = bf16(W[k][n]) for all three layers
__global__ __launch_bounds__(256) void wprep_kernel(const float* __restrict__ W1,
                                                    const float* __restrict__ W2,
                                                    const float* __restrict__ W3,
                                                    bf16_t* __restrict__ Wt1,
                                                    bf16_t* __restrict__ Wt2,
                                                    bf16_t* __restrict__ Wt3) {
    int i = blockIdx.x * 256 + threadIdx.x;
    if (i < 128 * IN_FEATS) {
        int n = i / IN_FEATS, k = i - n * IN_FEATS;
        Wt1[i] = f2bf(W1[k * 128 + n]);
        return;
    }
    i -= 128 * IN_FEATS;
    if (i < 128 * HIDDEN) {
        int n = i / HIDDEN, k = i - n * HIDDEN;
        Wt2[i] = f2bf(W2[k * 128 + n]);
        return;
    }
    i -= 128 * HIDDEN;
    if (i < 128 * HIDDEN) {
        int n = i / HIDDEN, k = i - n * HIDDEN;
        Wt3[i] = f2bf(W3[k * 128 + n]);
    }
}

__global__ __launch_bounds__(256) void prescale_kernel(const float* __restrict__ x,
                                                       const float* __restrict__ nsrc,
                                                       bf16_t* __restrict__ xb) {
    int i = blockIdx.x * 256 + threadIdx.x;
    const int total = N_NODES * (IN_FEATS / 4);
    if (i >= total) return;
    int node = i >> 4;                       // IN_FEATS/4 == 16
    float nm = nsrc[node];
    float4 v = ((const float4*)x)[i];
    ushort4 o;
    o.x = f2bf(v.x * nm); o.y = f2bf(v.y * nm);
    o.z = f2bf(v.z * nm); o.w = f2bf(v.w * nm);
    ((ushort4*)xb)[i] = o;
}

// ============ sliced gather: one 64-B (32-feat) column per pass ============
// Per pass the live line-set is N_NODES x 64 B = 6.4 MB (vs 25.6 MB whole-row),
// near XCD-L2 capacity. Requests/edge/pass = 1 line (8 lanes x 8 B). Passes
// are SEQUENTIAL dispatches so all CUs share one working set. Same total
// request count as single-pass whole-row gather; FETCH should drop sharply.
template <int K>
__global__ __launch_bounds__(256) void gatherS_kernel(const bf16_t* __restrict__ hb,
                                                      const int* __restrict__ rowptr,
                                                      const int* __restrict__ csr_src,
                                                      const float* __restrict__ ndst,
                                                      bf16_t* __restrict__ outb,
                                                      int pass) {
    const int l = threadIdx.x & 63;
    const int es = l >> 3;               // edge slot 0..7
    const int k8 = l & 7;                // feat quad within 32-feat slice
    const int node = (blockIdx.x * 256 + threadIdx.x) >> 6;
    if (node >= N_NODES) return;
    const bf16_t* bp = hb + pass * 32 + k8 * 4;
    const int r0 = rowptr[node], r1 = rowptr[node + 1];
    float a0 = 0.f, a1 = 0.f, a2 = 0.f, a3 = 0.f;
    for (int base = r0; base < r1; base += 64) {
        const int nb = min(64, r1 - base);
        int myidx = __builtin_nontemporal_load(&csr_src[base + min(l, nb - 1)]);
#pragma unroll 4
        for (int j = 0; j < nb; j += 8) {
            int e = j + es;
            int s = __shfl(myidx, min(e, nb - 1));
            if (e < nb) {
                ushort4 u = *(const ushort4*)(bp + (size_t)s * K);
                a0 += bf2f(u.x); a1 += bf2f(u.y); a2 += bf2f(u.z); a3 += bf2f(u.w);
            }
        }
    }
#pragma unroll
    for (int m = 8; m <= 32; m <<= 1) {
        a0 += __shfl_xor(a0, m); a1 += __shfl_xor(a1, m);
        a2 += __shfl_xor(a2, m); a3 += __shfl_xor(a3, m);
    }
    if (es == 0) {
        float nm = ndst[node];
        ushort4 o;
        o.x = f2bf(a0 * nm); o.y = f2bf(a1 * nm);
        o.z = f2bf(a2 * nm); o.w = f2bf(a3 * nm);
        *(ushort4*)(outb + (size_t)node * K + pass * 32 + k8 * 4) = o;
    }
}

// ============ MFMA node matmul: 2 row-tiles/block (stage sW once) ============
template <int K, bool SCALE_OUT>
__global__ __launch_bounds__(256) void node_matmul_mfma(const bf16_t* __restrict__ Hb,
                                                        const bf16_t* __restrict__ Wt,
                                                        const float* __restrict__ bias,
                                                        const float* __restrict__ nsrc,
                                                        bf16_t* __restrict__ outb) {
    __shared__ char sW[128 * K * 2];
    const int t = threadIdx.x;

    for (int fb = t * 16; fb < 128 * K * 2; fb += 256 * 16) {
        bfx8 v = *(const bfx8*)((const char*)Wt + fb);
        int n = fb / (2 * K);
        *(bfx8*)(sW + (fb ^ ((n & 7) << 4))) = v;
    }
    __syncthreads();

    const int wv = t >> 6;
    const int l  = t & 63;
    const int m  = l & 15;
    const int kb = l >> 4;

    for (int t2 = 0; t2 < 2; ++t2) {
        const int tile = blockIdx.x * 2 + t2;
        if (tile * 64 >= N_NODES) break;
        const int row0 = tile * 64 + wv * 16;

        int arow = row0 + m;
        if (arow > N_NODES - 1) arow = N_NODES - 1;
        const char* aptr = (const char*)(Hb + (size_t)arow * K);

        f32x4 acc[8];
#pragma unroll
        for (int f = 0; f < 8; ++f) acc[f] = (f32x4){0.f, 0.f, 0.f, 0.f};

#pragma unroll
        for (int kc = 0; kc < K / 32; ++kc) {
            bfx8 a = *(const bfx8*)(aptr + kc * 64 + kb * 16);
#pragma unroll
            for (int f = 0; f < 8; ++f) {
                int n = f * 16 + m;
                int off = n * (2 * K) + kc * 64 + kb * 16;
                off ^= (n & 7) << 4;
                bfx8 b = *(const bfx8*)(sW + off);
                acc[f] = __builtin_amdgcn_mfma_f32_16x16x32_bf16(a, b, acc[f], 0, 0, 0);
            }
        }

        int nodes[4];
        float nm[4];
#pragma unroll
        for (int j = 0; j < 4; ++j) {
            nodes[j] = row0 + kb * 4 + j;
            nm[j] = 1.f;
            if (SCALE_OUT && nodes[j] < N_NODES) nm[j] = nsrc[nodes[j]];
        }
#pragma unroll
        for (int f = 0; f < 8; ++f) {
            int feat = f * 16 + m;
            float bb = bias[feat];
#pragma unroll
            for (int j = 0; j < 4; ++j) {
                if (nodes[j] < N_NODES) {
                    float v = selu_f(acc[f][j] + bb) * nm[j];
                    outb[(size_t)nodes[j] * HIDDEN + feat] = f2bf(v);
                }
            }
        }
    }
}

// ============ pool + MLP head ============
__global__ __launch_bounds__(256) void pool_kernel(const bf16_t* __restrict__ h,
                                                   const int* __restrict__ gid,
                                                   float* __restrict__ emb,
                                                   float* __restrict__ cnt) {
    const int lane = threadIdx.x & 63;
    const int wid = (blockIdx.x * 256 + threadIdx.x) >> 6;
    const int n0 = wid * 64;
    if (n0 >= N_NODES) return;
    const int nend = (n0 + 64 < N_NODES) ? n0 + 64 : N_NODES;
    int cur = gid[n0];
    float ax = 0.f, ay = 0.f, run = 0.f;
    for (int n = n0; n < nend; ++n) {
        int g = gid[n];
        if (g != cur) {
            atomicAdd(&emb[(size_t)cur * HIDDEN + lane * 2], ax);
            atomicAdd(&emb[(size_t)cur * HIDDEN + lane * 2 + 1], ay);
            if (lane == 0) atomicAdd(&cnt[cur], run);
            cur = g; ax = 0.f; ay = 0.f; run = 0.f;
        }
        ushort2 u = *(const ushort2*)(h + (size_t)n * HIDDEN + lane * 2);
        ax += bf2f(u.x); ay += bf2f(u.y);
        run += 1.f;
    }
    atomicAdd(&emb[(size_t)cur * HIDDEN + lane * 2], ax);
    atomicAdd(&emb[(size_t)cur * HIDDEN + lane * 2 + 1], ay);
    if (lane == 0) atomicAdd(&cnt[cur], run);
}

__global__ __launch_bounds__(256) void mlp_kernel(const float* __restrict__ emb,
                                                  const float* __restrict__ cnt,
                                                  const float* __restrict__ fg,
                                                  const float* __restrict__ M1, const float* __restrict__ c1,
                                                  const float* __restrict__ M2, const float* __restrict__ c2,
                                                  const float* __restrict__ M3, const float* __restrict__ c3,
                                                  float* __restrict__ out) {
    const int g = blockIdx.x;
    const int t = threadIdx.x;
    __shared__ float z[HIDDEN + EXTRA];
    __shared__ float z1[2 * HIDDEN];
    __shared__ float z2[HIDDEN];
    if (t < HIDDEN) {
        float c = fmaxf(cnt[g], 1.f);
        z[t] = emb[(size_t)g * HIDDEN + t] / c;
    } else if (t < HIDDEN + EXTRA) {
        z[t] = fg[g * EXTRA + (t - HIDDEN)];
    }
    __syncthreads();
    {
        float s = c1[t];
        for (int k = 0; k < HIDDEN + EXTRA; ++k) s += z[k] * M1[k * (2 * HIDDEN) + t];
        z1[t] = selu_f(s);
    }
    __syncthreads();
    if (t < HIDDEN) {
        float s = c2[t];
        for (int k = 0; k < 2 * HIDDEN; ++k) s += z1[k] * M2[k * HIDDEN + t];
        z2[t] = selu_f(s);
    }
    __syncthreads();
    if (t < 64) {
        float s = z2[t] * M3[t] + z2[t + 64] * M3[t + 64];
#pragma unroll
        for (int off = 32; off; off >>= 1) s += __shfl_down(s, off);
        if (t == 0) out[g] = s + c3[0];
    }
}

extern "C" void kernel_launch(void* const* d_in, const int* in_sizes, int n_in,
                              void* d_out, int out_size, void* d_ws, size_t ws_size,
                              hipStream_t stream) {
    const float* feats_node  = (const float*)d_in[0];
    const float* feats_graph = (const float*)d_in[1];
    const int*   src         = (const int*)d_in[2];
    const int*   dst         = (const int*)d_in[3];
    const int*   gid         = (const int*)d_in[4];
    const float* W1 = (const float*)d_in[5];
    const float* b1 = (const float*)d_in[6];
    const float* W2 = (const float*)d_in[7];
    const float* b2 = (const float*)d_in[8];
    const float* W3 = (const float*)d_in[9];
    const float* b3 = (const float*)d_in[10];
    const float* M1 = (const float*)d_in[11];
    const float* c1 = (const float*)d_in[12];
    const float* M2 = (const float*)d_in[13];
    const float* c2 = (const float*)d_in[14];
    const float* M3 = (const float*)d_in[15];
    const float* c3 = (const float*)d_in[16];
    float* out = (float*)d_out;

    char* ws = (char*)d_ws;
    int* indeg   = (int*)ws;  ws += (size_t)N_NODES * sizeof(int);
    int* rowptr  = (int*)ws;  ws += (size_t)(N_NODES + 4) * sizeof(int);
    int* partials= (int*)ws;  ws += 512 * sizeof(int);
    float* norm_src = (float*)ws; ws += (size_t)N_NODES * sizeof(float);
    float* norm_dst = (float*)ws; ws += (size_t)N_NODES * sizeof(float);
    bf16_t* Wt1 = (bf16_t*)ws; ws += (size_t)128 * IN_FEATS * sizeof(bf16_t);
    bf16_t* Wt2 = (bf16_t*)ws; ws += (size_t)128 * HIDDEN * sizeof(bf16_t);
    bf16_t* Wt3 = (bf16_t*)ws; ws += (size_t)128 * HIDDEN * sizeof(bf16_t);
    int* csr_src = (int*)ws;  ws += (size_t)N_EDGES * sizeof(int);
    bf16_t* bufB = (bf16_t*)ws; ws += (size_t)N_NODES * HIDDEN * sizeof(bf16_t);
    // union 1: h_dst (alive histo..sortT) / bufA (alive after sortT)
    unsigned char* h_dst = (unsigned char*)ws;
    bf16_t* bufA = (bf16_t*)ws;
    ws += (size_t)G_SORT * N_NODES;                                  // 25.6 MB
    // union 2: h_src (alive histo..degs) / xb + emb + cnt
    unsigned char* h_src = (unsigned char*)ws;
    bf16_t* xb   = (bf16_t*)ws;
    float* emb   = (float*)(ws + (size_t)N_NODES * IN_FEATS * sizeof(bf16_t));
    float* cnt   = emb + (size_t)N_GRAPHS * HIDDEN;
    ws += (size_t)G_SORT * N_NODES;                                  // 25.6 MB

    // ---- CSR build (counting sort, no global atomics) ----
    histo_kernel<<<G_SORT, 512, 0, stream>>>(src, dst, h_src, h_dst);
    degs_kernel<<<NB_CHUNKS, 256, 0, stream>>>(h_src, h_dst, indeg, norm_src, norm_dst, partials);
    scanB<<<1, 512, 0, stream>>>(partials, rowptr);
    scanC<<<NB_CHUNKS, 256, 0, stream>>>(indeg, partials, rowptr);
    sortT_kernel<<<G_SORT, 512, 0, stream>>>(src, dst, h_dst, rowptr, csr_src);

    // ---- weight prep + prescale (xb overlays h_src: dead after degs) ----
    const int wtot = 128 * IN_FEATS + 2 * 128 * HIDDEN;
    wprep_kernel<<<(wtot + 255) / 256, 256, 0, stream>>>(W1, W2, W3, Wt1, Wt2, Wt3);
    prescale_kernel<<<(N_NODES * (IN_FEATS / 4) + 255) / 256, 256, 0, stream>>>(feats_node, norm_src, xb);

    const int mm_grid = (N_NODES + 127) / 128;   // 2 row-tiles of 64 per block
    const int g_grid  = (N_NODES + 3) / 4;       // 1 node/wave, 4 waves/block

    // layer 1: sliced gather(64, 2 passes) -> MFMA matmul w/ epilogue
    for (int p = 0; p < 2; ++p)
        gatherS_kernel<IN_FEATS><<<g_grid, 256, 0, stream>>>(xb, rowptr, csr_src, norm_dst, bufA, p);
    node_matmul_mfma<IN_FEATS, true><<<mm_grid, 256, 0, stream>>>(bufA, Wt1, b1, norm_src, bufB);

    // layer 2: sliced gather(128, 4 passes) -> matmul
    for (int p = 0; p < 4; ++p)
        gatherS_kernel<HIDDEN><<<g_grid, 256, 0, stream>>>(bufB, rowptr, csr_src, norm_dst, bufA, p);
    node_matmul_mfma<HIDDEN, true><<<mm_grid, 256, 0, stream>>>(bufA, Wt2, b2, norm_src, bufB);

    // layer 3 (no nsrc on output; feeds pooling)
    for (int p = 0; p < 4; ++p)
        gatherS_kernel<HIDDEN><<<g_grid, 256, 0, stream>>>(bufB, rowptr, csr_src, norm_dst, bufA, p);
    node_matmul_mfma<HIDDEN, false><<<mm_grid, 256, 0, stream>>>(bufA, Wt3, b3, norm_src, bufB);

    // readout + MLP (emb/cnt overlay xb tail region; xb dead after layer 1)
    hipMemsetAsync(emb, 0, ((size_t)N_GRAPHS * HIDDEN + N_GRAPHS) * sizeof(float), stream);
    const int n_waves = (N_NODES + 63) / 64;
    pool_kernel<<<(n_waves + 3) / 4, 256, 0, stream>>>(bufB, gid, emb, cnt);
    mlp_kernel<<<N_GRAPHS, 256, 0, stream>>>(emb, cnt, feats_graph,
                                             M1, c1, M2, c2, M3, c3, out);
}

// Round 13
// 669.412 us; speedup vs baseline: 1.7580x; 1.5444x over previous
//
#include <hip/hip_runtime.h>
#include <hip/hip_bf16.h>
#include <cstddef>

#define N_NODES 100000
#define N_EDGES 3200000
#define N_GRAPHS 2048
#define IN_FEATS 64
#define HIDDEN 128
#define EXTRA 8

#define SCAN_CHUNK 256
#define NB_CHUNKS ((N_NODES + SCAN_CHUNK - 1) / SCAN_CHUNK)  // 391

// counting-sort parameters: u8x4-packed LDS bins, 64000 bins/pass, 2 passes
#define R_BINS 64000
#define NPASS 2                      // 2 * 64000 >= 100000
#define G_SORT 256
#define CHUNK (N_EDGES / G_SORT)     // 12500

typedef unsigned short bf16_t;
typedef short bfx8 __attribute__((ext_vector_type(8)));
typedef float f32x4 __attribute__((ext_vector_type(4)));

__device__ __forceinline__ float selu_f(float x) {
    const float scale = 1.0507009873554805f;
    const float alpha = 1.6732632423543772f;
    return x > 0.f ? scale * x : scale * alpha * (__expf(x) - 1.f);
}
__device__ __forceinline__ float bf2f(unsigned short u) {
    union { unsigned int i; float f; } c; c.i = ((unsigned int)u) << 16; return c.f;
}
__device__ __forceinline__ unsigned short f2bf(float f) {
    union { float f; unsigned int i; } c; c.f = f;
    unsigned int lsb = (c.i >> 16) & 1;
    c.i += 0x7fffu + lsb;                 // round to nearest even
    return (unsigned short)(c.i >> 16);
}

// ============ counting-sort CSR build (no global atomics) ============

__global__ __launch_bounds__(512) void histo_kernel(const int* __restrict__ src,
                                                    const int* __restrict__ dst,
                                                    unsigned char* __restrict__ h_src,
                                                    unsigned char* __restrict__ h_dst) {
    __shared__ unsigned int hist[R_BINS / 4];   // 16000 words, 64000 B
    const int b = blockIdx.x, t = threadIdx.x;
    const int e0 = b * CHUNK;
#pragma unroll
    for (int ph = 0; ph < 2; ++ph) {
        const int4* key4 = (const int4*)((ph ? src : dst) + e0);
        unsigned char* hout = (ph ? h_src : h_dst) + (size_t)b * N_NODES;
        for (int p = 0; p < NPASS; ++p) {
            const int r0 = p * R_BINS;
            const int rend = min(R_BINS, N_NODES - r0);   // 64000 / 36000
            for (int i = t; i < R_BINS / 4; i += 512) hist[i] = 0;
            __syncthreads();
            for (int i = t; i < CHUNK / 4; i += 512) {
                int4 k = key4[i];
                unsigned int x;
                x = (unsigned)(k.x - r0); if (x < (unsigned)R_BINS) atomicAdd(&hist[x >> 2], 1u << ((x & 3) << 3));
                x = (unsigned)(k.y - r0); if (x < (unsigned)R_BINS) atomicAdd(&hist[x >> 2], 1u << ((x & 3) << 3));
                x = (unsigned)(k.z - r0); if (x < (unsigned)R_BINS) atomicAdd(&hist[x >> 2], 1u << ((x & 3) << 3));
                x = (unsigned)(k.w - r0); if (x < (unsigned)R_BINS) atomicAdd(&hist[x >> 2], 1u << ((x & 3) << 3));
            }
            __syncthreads();
            unsigned int* ho4 = (unsigned int*)(hout + r0);
            for (int i = t; i < rend / 4; i += 512) ho4[i] = hist[i];
            __syncthreads();
        }
    }
}

// merged: nsrc from colsum(h_src); h_dst -> in-place per-bin block prefix;
// indeg/ndst; block partial sums of indeg -> partials (scanA folded in)
__global__ __launch_bounds__(256) void degs_kernel(const unsigned char* __restrict__ h_src,
                                                   unsigned char* __restrict__ h_dst,
                                                   int* __restrict__ indeg,
                                                   float* __restrict__ nsrc,
                                                   float* __restrict__ ndst,
                                                   int* __restrict__ partials) {
    __shared__ int red[4];
    const int bin = blockIdx.x * 256 + threadIdx.x;
    int run = 0;
    if (bin < N_NODES) {
        int s = 0;
#pragma unroll 8
        for (int b = 0; b < G_SORT; ++b) s += h_src[(size_t)b * N_NODES + bin];
        nsrc[bin] = rsqrtf(fmaxf((float)s, 1.f));
#pragma unroll 8
        for (int b = 0; b < G_SORT; ++b) {
            size_t off = (size_t)b * N_NODES + bin;
            int v = h_dst[off];
            h_dst[off] = (unsigned char)run;
            run += v;
        }
        indeg[bin] = run;
        ndst[bin] = rsqrtf(fmaxf((float)run, 1.f));
    }
    int sum = run;
    for (int off = 32; off; off >>= 1) sum += __shfl_down(sum, off);
    if ((threadIdx.x & 63) == 0) red[threadIdx.x >> 6] = sum;
    __syncthreads();
    if (threadIdx.x == 0) partials[blockIdx.x] = red[0] + red[1] + red[2] + red[3];
}

__global__ __launch_bounds__(512) void sortT_kernel(const int* __restrict__ src,
                                                    const int* __restrict__ dst,
                                                    const unsigned char* __restrict__ h_dst,
                                                    const int* __restrict__ rowptr,
                                                    int* __restrict__ csr_src) {
    __shared__ unsigned int cnt[R_BINS / 4];   // 16000 words
    const int b = blockIdx.x, t = threadIdx.x;
    const int e0 = b * CHUNK;
    const int4* d4p = (const int4*)(dst + e0);
    const int4* s4p = (const int4*)(src + e0);
    const unsigned char* hrow = h_dst + (size_t)b * N_NODES;
    for (int p = 0; p < NPASS; ++p) {
        const int r0 = p * R_BINS;
        const int rend = min(R_BINS, N_NODES - r0);
        const unsigned int* hr4 = (const unsigned int*)(hrow + r0);
        for (int i = t; i < rend / 4; i += 512) cnt[i] = hr4[i];
        __syncthreads();
        for (int i = t; i < CHUNK / 4; i += 512) {
            int4 d = d4p[i];
            int4 s = s4p[i];
            unsigned int x, old, rank;
            x = (unsigned)(d.x - r0);
            if (x < (unsigned)R_BINS) {
                old = atomicAdd(&cnt[x >> 2], 1u << ((x & 3) << 3));
                rank = (old >> ((x & 3) << 3)) & 0xffu;
                csr_src[rowptr[d.x] + rank] = s.x;
            }
            x = (unsigned)(d.y - r0);
            if (x < (unsigned)R_BINS) {
                old = atomicAdd(&cnt[x >> 2], 1u << ((x & 3) << 3));
                rank = (old >> ((x & 3) << 3)) & 0xffu;
                csr_src[rowptr[d.y] + rank] = s.y;
            }
            x = (unsigned)(d.z - r0);
            if (x < (unsigned)R_BINS) {
                old = atomicAdd(&cnt[x >> 2], 1u << ((x & 3) << 3));
                rank = (old >> ((x & 3) << 3)) & 0xffu;
                csr_src[rowptr[d.z] + rank] = s.z;
            }
            x = (unsigned)(d.w - r0);
            if (x < (unsigned)R_BINS) {
                old = atomicAdd(&cnt[x >> 2], 1u << ((x & 3) << 3));
                rank = (old >> ((x & 3) << 3)) & 0xffu;
                csr_src[rowptr[d.w] + rank] = s.w;
            }
        }
        __syncthreads();
    }
}

// ============ rowptr scan ============

__global__ __launch_bounds__(512) void scanB(int* __restrict__ partials,
                                             int* __restrict__ rowptr) {
    __shared__ int s[512];
    const int t = threadIdx.x;
    int v = (t < NB_CHUNKS) ? partials[t] : 0;
    s[t] = v;
    __syncthreads();
    for (int off = 1; off < 512; off <<= 1) {
        int u = (t >= off) ? s[t - off] : 0;
        __syncthreads();
        s[t] += u;
        __syncthreads();
    }
    if (t < NB_CHUNKS) partials[t] = s[t] - v;   // exclusive
    if (t == 511) rowptr[N_NODES] = s[511];
}

__global__ __launch_bounds__(256) void scanC(const int* __restrict__ indeg,
                                             const int* __restrict__ partials,
                                             int* __restrict__ rowptr) {
    __shared__ int ts[256];
    const int b = blockIdx.x, t = threadIdx.x;
    const int i = b * 256 + t;
    int v = (i < N_NODES) ? indeg[i] : 0;
    ts[t] = v;
    __syncthreads();
    for (int off = 1; off < 256; off <<= 1) {
        int u = (t >= off) ? ts[t - off] : 0;
        __syncthreads();
        ts[t] += u;
        __syncthreads();
    }
    int excl = ts[t] - v + partials[b];
    if (i < N_NODES) rowptr[i] = excl;
}

// merged weight prep: Wt[n][k] = bf16(W[k][n]) for all three layers
__global__ __launch_bounds__(256) void wprep_kernel(const float* __restrict__ W1,
                                                    const float* __restrict__ W2,
                                                    const float* __restrict__ W3,
                                                    bf16_t* __restrict__ Wt1,
                                                    bf16_t* __restrict__ Wt2,
                                                    bf16_t* __restrict__ Wt3) {
    int i = blockIdx.x * 256 + threadIdx.x;
    if (i < 128 * IN_FEATS) {
        int n = i / IN_FEATS, k = i - n * IN_FEATS;
        Wt1[i] = f2bf(W1[k * 128 + n]);
        return;
    }
    i -= 128 * IN_FEATS;
    if (i < 128 * HIDDEN) {
        int n = i / HIDDEN, k = i - n * HIDDEN;
        Wt2[i] = f2bf(W2[k * 128 + n]);
        return;
    }
    i -= 128 * HIDDEN;
    if (i < 128 * HIDDEN) {
        int n = i / HIDDEN, k = i - n * HIDDEN;
        Wt3[i] = f2bf(W3[k * 128 + n]);
    }
}

__global__ __launch_bounds__(256) void prescale_kernel(const float* __restrict__ x,
                                                       const float* __restrict__ nsrc,
                                                       bf16_t* __restrict__ xb) {
    int i = blockIdx.x * 256 + threadIdx.x;
    const int total = N_NODES * (IN_FEATS / 4);
    if (i >= total) return;
    int node = i >> 4;                       // IN_FEATS/4 == 16
    float nm = nsrc[node];
    float4 v = ((const float4*)x)[i];
    ushort4 o;
    o.x = f2bf(v.x * nm); o.y = f2bf(v.y * nm);
    o.z = f2bf(v.z * nm); o.w = f2bf(v.w * nm);
    ((ushort4*)xb)[i] = o;
}

// ============ gathers (row-major, whole-row; measured-optimal r10 form) ============
__global__ __launch_bounds__(256) void gather64_kernel(const bf16_t* __restrict__ xb,
                                                       const int* __restrict__ rowptr,
                                                       const int* __restrict__ csr_src,
                                                       const float* __restrict__ ndst,
                                                       bf16_t* __restrict__ outb) {
    const int l = threadIdx.x & 63;
    const int q = l >> 4;                  // quarter 0..3
    const int s16 = l & 15;
    const int node = (blockIdx.x * 256 + threadIdx.x) >> 6;
    if (node >= N_NODES) return;
    const int r0 = rowptr[node], r1 = rowptr[node + 1];
    float a0 = 0.f, a1 = 0.f, a2 = 0.f, a3 = 0.f;
    for (int base = r0; base < r1; base += 16) {
        const int nb = min(16, r1 - base);
        int myidx = __builtin_nontemporal_load(&csr_src[base + min(s16, nb - 1)]);
#pragma unroll
        for (int j = 0; j < 16; j += 4) {
            if (j >= nb) break;
            int e = j + q;
            int s = __shfl(myidx, min(e, nb - 1));
            if (e < nb) {
                ushort4 u = *(const ushort4*)(xb + (size_t)s * IN_FEATS + s16 * 4);
                a0 += bf2f(u.x); a1 += bf2f(u.y); a2 += bf2f(u.z); a3 += bf2f(u.w);
            }
        }
    }
    a0 += __shfl_xor(a0, 16); a1 += __shfl_xor(a1, 16);
    a2 += __shfl_xor(a2, 16); a3 += __shfl_xor(a3, 16);
    a0 += __shfl_xor(a0, 32); a1 += __shfl_xor(a1, 32);
    a2 += __shfl_xor(a2, 32); a3 += __shfl_xor(a3, 32);
    if (q == 0) {
        float nm = ndst[node];
        ushort4 o;
        o.x = f2bf(a0 * nm); o.y = f2bf(a1 * nm);
        o.z = f2bf(a2 * nm); o.w = f2bf(a3 * nm);
        *(ushort4*)(outb + (size_t)node * IN_FEATS + s16 * 4) = o;
    }
}

__global__ __launch_bounds__(256) void gather128_kernel(const bf16_t* __restrict__ hb,
                                                        const int* __restrict__ rowptr,
                                                        const int* __restrict__ csr_src,
                                                        const float* __restrict__ ndst,
                                                        bf16_t* __restrict__ outb) {
    const int l = threadIdx.x & 63;
    const int half = l >> 5;
    const int sub = l & 31;
    const int node = (blockIdx.x * 256 + threadIdx.x) >> 6;
    if (node >= N_NODES) return;
    const int r0 = rowptr[node], r1 = rowptr[node + 1];
    float a0 = 0.f, a1 = 0.f, a2 = 0.f, a3 = 0.f;
    for (int base = r0; base < r1; base += 32) {
        const int nb = min(32, r1 - base);
        int myidx = __builtin_nontemporal_load(&csr_src[base + min(sub, nb - 1)]);
#pragma unroll 8
        for (int j = 0; j < nb; j += 2) {
            int e = j + half;
            int s = __shfl(myidx, min(e, nb - 1));
            if (e < nb) {
                ushort4 u = *(const ushort4*)(hb + (size_t)s * HIDDEN + sub * 4);
                a0 += bf2f(u.x); a1 += bf2f(u.y); a2 += bf2f(u.z); a3 += bf2f(u.w);
            }
        }
    }
    a0 += __shfl_xor(a0, 32); a1 += __shfl_xor(a1, 32);
    a2 += __shfl_xor(a2, 32); a3 += __shfl_xor(a3, 32);
    if (half == 0) {
        float nm = ndst[node];
        ushort4 o;
        o.x = f2bf(a0 * nm); o.y = f2bf(a1 * nm);
        o.z = f2bf(a2 * nm); o.w = f2bf(a3 * nm);
        *(ushort4*)(outb + (size_t)node * HIDDEN + sub * 4) = o;
    }
}

// ============ MFMA node matmul: 2 row-tiles/block (stage sW once) ============
template <int K, bool SCALE_OUT>
__global__ __launch_bounds__(256) void node_matmul_mfma(const bf16_t* __restrict__ Hb,
                                                        const bf16_t* __restrict__ Wt,
                                                        const float* __restrict__ bias,
                                                        const float* __restrict__ nsrc,
                                                        bf16_t* __restrict__ outb) {
    __shared__ char sW[128 * K * 2];
    const int t = threadIdx.x;

    for (int fb = t * 16; fb < 128 * K * 2; fb += 256 * 16) {
        bfx8 v = *(const bfx8*)((const char*)Wt + fb);
        int n = fb / (2 * K);
        *(bfx8*)(sW + (fb ^ ((n & 7) << 4))) = v;
    }
    __syncthreads();

    const int wv = t >> 6;
    const int l  = t & 63;
    const int m  = l & 15;
    const int kb = l >> 4;

    for (int t2 = 0; t2 < 2; ++t2) {
        const int tile = blockIdx.x * 2 + t2;
        if (tile * 64 >= N_NODES) break;
        const int row0 = tile * 64 + wv * 16;

        int arow = row0 + m;
        if (arow > N_NODES - 1) arow = N_NODES - 1;
        const char* aptr = (const char*)(Hb + (size_t)arow * K);

        f32x4 acc[8];
#pragma unroll
        for (int f = 0; f < 8; ++f) acc[f] = (f32x4){0.f, 0.f, 0.f, 0.f};

#pragma unroll
        for (int kc = 0; kc < K / 32; ++kc) {
            bfx8 a = *(const bfx8*)(aptr + kc * 64 + kb * 16);
#pragma unroll
            for (int f = 0; f < 8; ++f) {
                int n = f * 16 + m;
                int off = n * (2 * K) + kc * 64 + kb * 16;
                off ^= (n & 7) << 4;
                bfx8 b = *(const bfx8*)(sW + off);
                acc[f] = __builtin_amdgcn_mfma_f32_16x16x32_bf16(a, b, acc[f], 0, 0, 0);
            }
        }

        int nodes[4];
        float nm[4];
#pragma unroll
        for (int j = 0; j < 4; ++j) {
            nodes[j] = row0 + kb * 4 + j;
            nm[j] = 1.f;
            if (SCALE_OUT && nodes[j] < N_NODES) nm[j] = nsrc[nodes[j]];
        }
#pragma unroll
        for (int f = 0; f < 8; ++f) {
            int feat = f * 16 + m;
            float bb = bias[feat];
#pragma unroll
            for (int j = 0; j < 4; ++j) {
                if (nodes[j] < N_NODES) {
                    float v = selu_f(acc[f][j] + bb) * nm[j];
                    outb[(size_t)nodes[j] * HIDDEN + feat] = f2bf(v);
                }
            }
        }
    }
}

// ============ pool + MLP head ============
__global__ __launch_bounds__(256) void pool_kernel(const bf16_t* __restrict__ h,
                                                   const int* __restrict__ gid,
                                                   float* __restrict__ emb,
                                                   float* __restrict__ cnt) {
    const int lane = threadIdx.x & 63;
    const int wid = (blockIdx.x * 256 + threadIdx.x) >> 6;
    const int n0 = wid * 64;
    if (n0 >= N_NODES) return;
    const int nend = (n0 + 64 < N_NODES) ? n0 + 64 : N_NODES;
    int cur = gid[n0];
    float ax = 0.f, ay = 0.f, run = 0.f;
    for (int n = n0; n < nend; ++n) {
        int g = gid[n];
        if (g != cur) {
            atomicAdd(&emb[(size_t)cur * HIDDEN + lane * 2], ax);
            atomicAdd(&emb[(size_t)cur * HIDDEN + lane * 2 + 1], ay);
            if (lane == 0) atomicAdd(&cnt[cur], run);
            cur = g; ax = 0.f; ay = 0.f; run = 0.f;
        }
        ushort2 u = *(const ushort2*)(h + (size_t)n * HIDDEN + lane * 2);
        ax += bf2f(u.x); ay += bf2f(u.y);
        run += 1.f;
    }
    atomicAdd(&emb[(size_t)cur * HIDDEN + lane * 2], ax);
    atomicAdd(&emb[(size_t)cur * HIDDEN + lane * 2 + 1], ay);
    if (lane == 0) atomicAdd(&cnt[cur], run);
}

__global__ __launch_bounds__(256) void mlp_kernel(const float* __restrict__ emb,
                                                  const float* __restrict__ cnt,
                                                  const float* __restrict__ fg,
                                                  const float* __restrict__ M1, const float* __restrict__ c1,
                                                  const float* __restrict__ M2, const float* __restrict__ c2,
                                                  const float* __restrict__ M3, const float* __restrict__ c3,
                                                  float* __restrict__ out) {
    const int g = blockIdx.x;
    const int t = threadIdx.x;
    __shared__ float z[HIDDEN + EXTRA];
    __shared__ float z1[2 * HIDDEN];
    __shared__ float z2[HIDDEN];
    if (t < HIDDEN) {
        float c = fmaxf(cnt[g], 1.f);
        z[t] = emb[(size_t)g * HIDDEN + t] / c;
    } else if (t < HIDDEN + EXTRA) {
        z[t] = fg[g * EXTRA + (t - HIDDEN)];
    }
    __syncthreads();
    {
        float s = c1[t];
        for (int k = 0; k < HIDDEN + EXTRA; ++k) s += z[k] * M1[k * (2 * HIDDEN) + t];
        z1[t] = selu_f(s);
    }
    __syncthreads();
    if (t < HIDDEN) {
        float s = c2[t];
        for (int k = 0; k < 2 * HIDDEN; ++k) s += z1[k] * M2[k * HIDDEN + t];
        z2[t] = selu_f(s);
    }
    __syncthreads();
    if (t < 64) {
        float s = z2[t] * M3[t] + z2[t + 64] * M3[t + 64];
#pragma unroll
        for (int off = 32; off; off >>= 1) s += __shfl_down(s, off);
        if (t == 0) out[g] = s + c3[0];
    }
}

extern "C" void kernel_launch(void* const* d_in, const int* in_sizes, int n_in,
                              void* d_out, int out_size, void* d_ws, size_t ws_size,
                              hipStream_t stream) {
    const float* feats_node  = (const float*)d_in[0];
    const float* feats_graph = (const float*)d_in[1];
    const int*   src         = (const int*)d_in[2];
    const int*   dst         = (const int*)d_in[3];
    const int*   gid         = (const int*)d_in[4];
    const float* W1 = (const float*)d_in[5];
    const float* b1 = (const float*)d_in[6];
    const float* W2 = (const float*)d_in[7];
    const float* b2 = (const float*)d_in[8];
    const float* W3 = (const float*)d_in[9];
    const float* b3 = (const float*)d_in[10];
    const float* M1 = (const float*)d_in[11];
    const float* c1 = (const float*)d_in[12];
    const float* M2 = (const float*)d_in[13];
    const float* c2 = (const float*)d_in[14];
    const float* M3 = (const float*)d_in[15];
    const float* c3 = (const float*)d_in[16];
    float* out = (float*)d_out;

    char* ws = (char*)d_ws;
    int* indeg   = (int*)ws;  ws += (size_t)N_NODES * sizeof(int);
    int* rowptr  = (int*)ws;  ws += (size_t)(N_NODES + 4) * sizeof(int);
    int* partials= (int*)ws;  ws += 512 * sizeof(int);
    float* norm_src = (float*)ws; ws += (size_t)N_NODES * sizeof(float);
    float* norm_dst = (float*)ws; ws += (size_t)N_NODES * sizeof(float);
    bf16_t* Wt1 = (bf16_t*)ws; ws += (size_t)128 * IN_FEATS * sizeof(bf16_t);
    bf16_t* Wt2 = (bf16_t*)ws; ws += (size_t)128 * HIDDEN * sizeof(bf16_t);
    bf16_t* Wt3 = (bf16_t*)ws; ws += (size_t)128 * HIDDEN * sizeof(bf16_t);
    int* csr_src = (int*)ws;  ws += (size_t)N_EDGES * sizeof(int);
    bf16_t* bufB = (bf16_t*)ws; ws += (size_t)N_NODES * HIDDEN * sizeof(bf16_t);
    // union 1: h_dst (alive histo..sortT) / bufA (alive after sortT)
    unsigned char* h_dst = (unsigned char*)ws;
    bf16_t* bufA = (bf16_t*)ws;
    ws += (size_t)G_SORT * N_NODES;                                  // 25.6 MB
    // union 2: h_src (alive histo..degs) / xb + emb + cnt
    unsigned char* h_src = (unsigned char*)ws;
    bf16_t* xb   = (bf16_t*)ws;
    float* emb   = (float*)(ws + (size_t)N_NODES * IN_FEATS * sizeof(bf16_t));
    float* cnt   = emb + (size_t)N_GRAPHS * HIDDEN;
    ws += (size_t)G_SORT * N_NODES;                                  // 25.6 MB

    // ---- CSR build (counting sort, no global atomics) ----
    histo_kernel<<<G_SORT, 512, 0, stream>>>(src, dst, h_src, h_dst);
    degs_kernel<<<NB_CHUNKS, 256, 0, stream>>>(h_src, h_dst, indeg, norm_src, norm_dst, partials);
    scanB<<<1, 512, 0, stream>>>(partials, rowptr);
    scanC<<<NB_CHUNKS, 256, 0, stream>>>(indeg, partials, rowptr);
    sortT_kernel<<<G_SORT, 512, 0, stream>>>(src, dst, h_dst, rowptr, csr_src);

    // ---- weight prep + prescale (xb overlays h_src: dead after degs) ----
    const int wtot = 128 * IN_FEATS + 2 * 128 * HIDDEN;
    wprep_kernel<<<(wtot + 255) / 256, 256, 0, stream>>>(W1, W2, W3, Wt1, Wt2, Wt3);
    prescale_kernel<<<(N_NODES * (IN_FEATS / 4) + 255) / 256, 256, 0, stream>>>(feats_node, norm_src, xb);

    const int mm_grid = (N_NODES + 127) / 128;   // 2 row-tiles of 64 per block
    const int g_grid  = (N_NODES + 3) / 4;       // 1 node/wave, 4 waves/block

    // layer 1: aggregate(64) -> MFMA matmul(64->128) w/ selu+bias+nsrc epilogue
    gather64_kernel<<<g_grid, 256, 0, stream>>>(xb, rowptr, csr_src, norm_dst, bufA);
    node_matmul_mfma<IN_FEATS, true><<<mm_grid, 256, 0, stream>>>(bufA, Wt1, b1, norm_src, bufB);

    // layer 2
    gather128_kernel<<<g_grid, 256, 0, stream>>>(bufB, rowptr, csr_src, norm_dst, bufA);
    node_matmul_mfma<HIDDEN, true><<<mm_grid, 256, 0, stream>>>(bufA, Wt2, b2, norm_src, bufB);

    // layer 3 (no nsrc on output; feeds pooling)
    gather128_kernel<<<g_grid, 256, 0, stream>>>(bufB, rowptr, csr_src, norm_dst, bufA);
    node_matmul_mfma<HIDDEN, false><<<mm_grid, 256, 0, stream>>>(bufA, Wt3, b3, norm_src, bufB);

    // readout + MLP (emb/cnt overlay xb tail region; xb dead after layer 1)
    hipMemsetAsync(emb, 0, ((size_t)N_GRAPHS * HIDDEN + N_GRAPHS) * sizeof(float), stream);
    const int n_waves = (N_NODES + 63) / 64;
    pool_kernel<<<(n_waves + 3) / 4, 256, 0, stream>>>(bufB, gid, emb, cnt);
    mlp_kernel<<<N_GRAPHS, 256, 0, stream>>>(emb, cnt, feats_graph,
                                             M1, c1, M2, c2, M3, c3, out);
}

// Round 14
// 647.383 us; speedup vs baseline: 1.8179x; 1.0340x over previous
//
#include <hip/hip_runtime.h>
#include <hip/hip_bf16.h>
#include <cstddef>

#define N_NODES 100000
#define N_EDGES 3200000
#define N_GRAPHS 2048
#define IN_FEATS 64
#define HIDDEN 128
#define EXTRA 8

#define SCAN_CHUNK 1024
#define NB_CHUNKS ((N_NODES + SCAN_CHUNK - 1) / SCAN_CHUNK)  // 98

// counting-sort parameters: u8x4-packed LDS bins, 64000 bins/pass, 2 passes
#define R_BINS 64000
#define NPASS 2                      // 2 * 64000 >= 100000
#define G_SORT 256
#define CHUNK (N_EDGES / G_SORT)     // 12500

typedef unsigned short bf16_t;
typedef short bfx8 __attribute__((ext_vector_type(8)));
typedef float f32x4 __attribute__((ext_vector_type(4)));

__device__ __forceinline__ float selu_f(float x) {
    const float scale = 1.0507009873554805f;
    const float alpha = 1.6732632423543772f;
    return x > 0.f ? scale * x : scale * alpha * (__expf(x) - 1.f);
}
__device__ __forceinline__ float bf2f(unsigned short u) {
    union { unsigned int i; float f; } c; c.i = ((unsigned int)u) << 16; return c.f;
}
__device__ __forceinline__ unsigned short f2bf(float f) {
    union { float f; unsigned int i; } c; c.f = f;
    unsigned int lsb = (c.i >> 16) & 1;
    c.i += 0x7fffu + lsb;                 // round to nearest even
    return (unsigned short)(c.i >> 16);
}

// ============ counting-sort CSR build (no global atomics) ============
// u8x4-packed histogram: 64000 bins/pass in 16000 u32 words. Per-(block,bin)
// count <= ~8 (Poisson lambda 0.195) and per-bin rank <= indeg_max ~70 -> u8
// safe, no byte carry.

__global__ __launch_bounds__(512) void histo_kernel(const int* __restrict__ src,
                                                    const int* __restrict__ dst,
                                                    unsigned char* __restrict__ h_src,
                                                    unsigned char* __restrict__ h_dst) {
    __shared__ unsigned int hist[R_BINS / 4];   // 16000 words, 64000 B
    const int b = blockIdx.x, t = threadIdx.x;
    const int e0 = b * CHUNK;
#pragma unroll
    for (int ph = 0; ph < 2; ++ph) {
        const int4* key4 = (const int4*)((ph ? src : dst) + e0);
        unsigned char* hout = (ph ? h_src : h_dst) + (size_t)b * N_NODES;
        for (int p = 0; p < NPASS; ++p) {
            const int r0 = p * R_BINS;
            const int rend = min(R_BINS, N_NODES - r0);   // 64000 / 36000
            for (int i = t; i < R_BINS / 4; i += 512) hist[i] = 0;
            __syncthreads();
            for (int i = t; i < CHUNK / 4; i += 512) {
                int4 k = key4[i];
                unsigned int x;
                x = (unsigned)(k.x - r0); if (x < (unsigned)R_BINS) atomicAdd(&hist[x >> 2], 1u << ((x & 3) << 3));
                x = (unsigned)(k.y - r0); if (x < (unsigned)R_BINS) atomicAdd(&hist[x >> 2], 1u << ((x & 3) << 3));
                x = (unsigned)(k.z - r0); if (x < (unsigned)R_BINS) atomicAdd(&hist[x >> 2], 1u << ((x & 3) << 3));
                x = (unsigned)(k.w - r0); if (x < (unsigned)R_BINS) atomicAdd(&hist[x >> 2], 1u << ((x & 3) << 3));
            }
            __syncthreads();
            unsigned int* ho4 = (unsigned int*)(hout + r0);
            for (int i = t; i < rend / 4; i += 512) ho4[i] = hist[i];
            __syncthreads();
        }
    }
}

// merged: outdeg/nsrc = colsum(h_src); h_dst -> in-place per-bin block prefix;
// indeg/ndst = total
__global__ __launch_bounds__(256) void degs_kernel(const unsigned char* __restrict__ h_src,
                                                   unsigned char* __restrict__ h_dst,
                                                   int* __restrict__ indeg,
                                                   float* __restrict__ nsrc,
                                                   float* __restrict__ ndst) {
    int bin = blockIdx.x * 256 + threadIdx.x;
    if (bin >= N_NODES) return;
    int s = 0;
#pragma unroll 8
    for (int b = 0; b < G_SORT; ++b) s += h_src[(size_t)b * N_NODES + bin];
    nsrc[bin] = rsqrtf(fmaxf((float)s, 1.f));
    int run = 0;
#pragma unroll 8
    for (int b = 0; b < G_SORT; ++b) {
        size_t off = (size_t)b * N_NODES + bin;
        int v = h_dst[off];
        h_dst[off] = (unsigned char)run;
        run += v;
    }
    indeg[bin] = run;
    ndst[bin] = rsqrtf(fmaxf((float)run, 1.f));
}

// 2-pass scatter: rank from u8x4-packed LDS counters; slot = rowptr[d] + rank
__global__ __launch_bounds__(512) void sortT_kernel(const int* __restrict__ src,
                                                    const int* __restrict__ dst,
                                                    const unsigned char* __restrict__ h_dst,
                                                    const int* __restrict__ rowptr,
                                                    int* __restrict__ csr_src) {
    __shared__ unsigned int cnt[R_BINS / 4];   // 16000 words
    const int b = blockIdx.x, t = threadIdx.x;
    const int e0 = b * CHUNK;
    const int4* d4p = (const int4*)(dst + e0);
    const int4* s4p = (const int4*)(src + e0);
    const unsigned char* hrow = h_dst + (size_t)b * N_NODES;
    for (int p = 0; p < NPASS; ++p) {
        const int r0 = p * R_BINS;
        const int rend = min(R_BINS, N_NODES - r0);
        const unsigned int* hr4 = (const unsigned int*)(hrow + r0);
        for (int i = t; i < rend / 4; i += 512) cnt[i] = hr4[i];
        __syncthreads();
        for (int i = t; i < CHUNK / 4; i += 512) {
            int4 d = d4p[i];
            int4 s = s4p[i];
            unsigned int x, old, rank;
            x = (unsigned)(d.x - r0);
            if (x < (unsigned)R_BINS) {
                old = atomicAdd(&cnt[x >> 2], 1u << ((x & 3) << 3));
                rank = (old >> ((x & 3) << 3)) & 0xffu;
                csr_src[rowptr[d.x] + rank] = s.x;
            }
            x = (unsigned)(d.y - r0);
            if (x < (unsigned)R_BINS) {
                old = atomicAdd(&cnt[x >> 2], 1u << ((x & 3) << 3));
                rank = (old >> ((x & 3) << 3)) & 0xffu;
                csr_src[rowptr[d.y] + rank] = s.y;
            }
            x = (unsigned)(d.z - r0);
            if (x < (unsigned)R_BINS) {
                old = atomicAdd(&cnt[x >> 2], 1u << ((x & 3) << 3));
                rank = (old >> ((x & 3) << 3)) & 0xffu;
                csr_src[rowptr[d.z] + rank] = s.z;
            }
            x = (unsigned)(d.w - r0);
            if (x < (unsigned)R_BINS) {
                old = atomicAdd(&cnt[x >> 2], 1u << ((x & 3) << 3));
                rank = (old >> ((x & 3) << 3)) & 0xffu;
                csr_src[rowptr[d.w] + rank] = s.w;
            }
        }
        __syncthreads();
    }
}

// ============ rowptr scan ============

__global__ __launch_bounds__(256) void scanA(const int* __restrict__ indeg,
                                             int* __restrict__ partials) {
    __shared__ int red[4];
    const int b = blockIdx.x, t = threadIdx.x;
    int base = b * SCAN_CHUNK + t * 4;
    int s = 0;
#pragma unroll
    for (int k = 0; k < 4; ++k) { int i = base + k; if (i < N_NODES) s += indeg[i]; }
    for (int off = 32; off; off >>= 1) s += __shfl_down(s, off);
    if ((t & 63) == 0) red[t >> 6] = s;
    __syncthreads();
    if (t == 0) partials[b] = red[0] + red[1] + red[2] + red[3];
}

__global__ __launch_bounds__(128) void scanB(int* __restrict__ partials,
                                             int* __restrict__ rowptr) {
    __shared__ int s[128];
    const int t = threadIdx.x;
    int v = (t < NB_CHUNKS) ? partials[t] : 0;
    s[t] = v;
    __syncthreads();
    for (int off = 1; off < 128; off <<= 1) {
        int u = (t >= off) ? s[t - off] : 0;
        __syncthreads();
        s[t] += u;
        __syncthreads();
    }
    if (t < NB_CHUNKS) partials[t] = s[t] - v;   // exclusive
    if (t == 127) rowptr[N_NODES] = s[127];
}

__global__ __launch_bounds__(256) void scanC(const int* __restrict__ indeg,
                                             const int* __restrict__ partials,
                                             int* __restrict__ rowptr) {
    __shared__ int ts[256];
    const int b = blockIdx.x, t = threadIdx.x;
    int base = b * SCAN_CHUNK + t * 4;
    int v[4];
    int s = 0;
#pragma unroll
    for (int k = 0; k < 4; ++k) { int i = base + k; v[k] = (i < N_NODES) ? indeg[i] : 0; s += v[k]; }
    ts[t] = s;
    __syncthreads();
    for (int off = 1; off < 256; off <<= 1) {
        int u = (t >= off) ? ts[t - off] : 0;
        __syncthreads();
        ts[t] += u;
        __syncthreads();
    }
    int excl = ts[t] - s + partials[b];
#pragma unroll
    for (int k = 0; k < 4; ++k) {
        int i = base + k;
        if (i < N_NODES) rowptr[i] = excl;
        excl += v[k];
    }
}

__global__ __launch_bounds__(256) void wprep_kernel(const float* __restrict__ W,
                                                    bf16_t* __restrict__ Wt, int K) {
    int i = blockIdx.x * 256 + threadIdx.x;
    if (i >= 128 * K) return;
    int n = i / K, k = i - n * K;
    Wt[i] = f2bf(W[k * 128 + n]);
}

__global__ __launch_bounds__(256) void prescale_kernel(const float* __restrict__ x,
                                                       const float* __restrict__ nsrc,
                                                       bf16_t* __restrict__ xb) {
    int i = blockIdx.x * 256 + threadIdx.x;
    const int total = N_NODES * (IN_FEATS / 4);
    if (i >= total) return;
    int node = i >> 4;                       // IN_FEATS/4 == 16
    float nm = nsrc[node];
    float4 v = ((const float4*)x)[i];
    ushort4 o;
    o.x = f2bf(v.x * nm); o.y = f2bf(v.y * nm);
    o.z = f2bf(v.z * nm); o.w = f2bf(v.w * nm);
    ((ushort4*)xb)[i] = o;
}

// ============ gathers (row-major, request-count-optimal; NT csr stream) ============
__global__ __launch_bounds__(256) void gather64_kernel(const bf16_t* __restrict__ xb,
                                                       const int* __restrict__ rowptr,
                                                       const int* __restrict__ csr_src,
                                                       const float* __restrict__ ndst,
                                                       bf16_t* __restrict__ outb) {
    const int l = threadIdx.x & 63;
    const int q = l >> 4;                  // quarter 0..3
    const int s16 = l & 15;
    const int node = (blockIdx.x * 256 + threadIdx.x) >> 6;
    if (node >= N_NODES) return;
    const int r0 = rowptr[node], r1 = rowptr[node + 1];
    float a0 = 0.f, a1 = 0.f, a2 = 0.f, a3 = 0.f;
    for (int base = r0; base < r1; base += 16) {
        const int nb = min(16, r1 - base);
        int myidx = __builtin_nontemporal_load(&csr_src[base + min(s16, nb - 1)]);
#pragma unroll
        for (int j = 0; j < 16; j += 4) {
            if (j >= nb) break;
            int e = j + q;
            int s = __shfl(myidx, min(e, nb - 1));
            if (e < nb) {
                ushort4 u = *(const ushort4*)(xb + (size_t)s * IN_FEATS + s16 * 4);
                a0 += bf2f(u.x); a1 += bf2f(u.y); a2 += bf2f(u.z); a3 += bf2f(u.w);
            }
        }
    }
    a0 += __shfl_xor(a0, 16); a1 += __shfl_xor(a1, 16);
    a2 += __shfl_xor(a2, 16); a3 += __shfl_xor(a3, 16);
    a0 += __shfl_xor(a0, 32); a1 += __shfl_xor(a1, 32);
    a2 += __shfl_xor(a2, 32); a3 += __shfl_xor(a3, 32);
    if (q == 0) {
        float nm = ndst[node];
        ushort4 o;
        o.x = f2bf(a0 * nm); o.y = f2bf(a1 * nm);
        o.z = f2bf(a2 * nm); o.w = f2bf(a3 * nm);
        *(ushort4*)(outb + (size_t)node * IN_FEATS + s16 * 4) = o;
    }
}

__global__ __launch_bounds__(256) void gather128_kernel(const bf16_t* __restrict__ hb,
                                                        const int* __restrict__ rowptr,
                                                        const int* __restrict__ csr_src,
                                                        const float* __restrict__ ndst,
                                                        bf16_t* __restrict__ outb) {
    const int l = threadIdx.x & 63;
    const int half = l >> 5;
    const int sub = l & 31;
    const int node = (blockIdx.x * 256 + threadIdx.x) >> 6;
    if (node >= N_NODES) return;
    const int r0 = rowptr[node], r1 = rowptr[node + 1];
    float a0 = 0.f, a1 = 0.f, a2 = 0.f, a3 = 0.f;
    for (int base = r0; base < r1; base += 32) {
        const int nb = min(32, r1 - base);
        int myidx = __builtin_nontemporal_load(&csr_src[base + min(sub, nb - 1)]);
#pragma unroll 8
        for (int j = 0; j < nb; j += 2) {
            int e = j + half;
            int s = __shfl(myidx, min(e, nb - 1));
            if (e < nb) {
                ushort4 u = *(const ushort4*)(hb + (size_t)s * HIDDEN + sub * 4);
                a0 += bf2f(u.x); a1 += bf2f(u.y); a2 += bf2f(u.z); a3 += bf2f(u.w);
            }
        }
    }
    a0 += __shfl_xor(a0, 32); a1 += __shfl_xor(a1, 32);
    a2 += __shfl_xor(a2, 32); a3 += __shfl_xor(a3, 32);
    if (half == 0) {
        float nm = ndst[node];
        ushort4 o;
        o.x = f2bf(a0 * nm); o.y = f2bf(a1 * nm);
        o.z = f2bf(a2 * nm); o.w = f2bf(a3 * nm);
        *(ushort4*)(outb + (size_t)node * HIDDEN + sub * 4) = o;
    }
}

// ============ MFMA node matmul (row-major in/out, fused epilogue) ============
template <int K, bool SCALE_OUT>
__global__ __launch_bounds__(256) void node_matmul_mfma(const bf16_t* __restrict__ Hb,
                                                        const bf16_t* __restrict__ Wt,
                                                        const float* __restrict__ bias,
                                                        const float* __restrict__ nsrc,
                                                        bf16_t* __restrict__ outb) {
    __shared__ char sW[128 * K * 2];
    const int t = threadIdx.x;

    for (int fb = t * 16; fb < 128 * K * 2; fb += 256 * 16) {
        bfx8 v = *(const bfx8*)((const char*)Wt + fb);
        int n = fb / (2 * K);
        *(bfx8*)(sW + (fb ^ ((n & 7) << 4))) = v;
    }
    __syncthreads();

    const int wv = t >> 6;
    const int l  = t & 63;
    const int m  = l & 15;
    const int kb = l >> 4;
    const int row0 = blockIdx.x * 64 + wv * 16;

    int arow = row0 + m;
    if (arow > N_NODES - 1) arow = N_NODES - 1;
    const char* aptr = (const char*)(Hb + (size_t)arow * K);

    f32x4 acc[8];
#pragma unroll
    for (int f = 0; f < 8; ++f) acc[f] = (f32x4){0.f, 0.f, 0.f, 0.f};

#pragma unroll
    for (int kc = 0; kc < K / 32; ++kc) {
        bfx8 a = *(const bfx8*)(aptr + kc * 64 + kb * 16);
#pragma unroll
        for (int f = 0; f < 8; ++f) {
            int n = f * 16 + m;
            int off = n * (2 * K) + kc * 64 + kb * 16;
            off ^= (n & 7) << 4;
            bfx8 b = *(const bfx8*)(sW + off);
            acc[f] = __builtin_amdgcn_mfma_f32_16x16x32_bf16(a, b, acc[f], 0, 0, 0);
        }
    }

    int nodes[4];
    float nm[4];
#pragma unroll
    for (int j = 0; j < 4; ++j) {
        nodes[j] = row0 + kb * 4 + j;
        nm[j] = 1.f;
        if (SCALE_OUT && nodes[j] < N_NODES) nm[j] = nsrc[nodes[j]];
    }
#pragma unroll
    for (int f = 0; f < 8; ++f) {
        int feat = f * 16 + m;
        float bb = bias[feat];
#pragma unroll
        for (int j = 0; j < 4; ++j) {
            if (nodes[j] < N_NODES) {
                float v = selu_f(acc[f][j] + bb) * nm[j];
                outb[(size_t)nodes[j] * HIDDEN + feat] = f2bf(v);
            }
        }
    }
}

// ============ pool + MLP head ============
__global__ __launch_bounds__(256) void pool_kernel(const bf16_t* __restrict__ h,
                                                   const int* __restrict__ gid,
                                                   float* __restrict__ emb,
                                                   float* __restrict__ cnt) {
    const int lane = threadIdx.x & 63;
    const int wid = (blockIdx.x * 256 + threadIdx.x) >> 6;
    const int n0 = wid * 64;
    if (n0 >= N_NODES) return;
    const int nend = (n0 + 64 < N_NODES) ? n0 + 64 : N_NODES;
    int cur = gid[n0];
    float ax = 0.f, ay = 0.f, run = 0.f;
    for (int n = n0; n < nend; ++n) {
        int g = gid[n];
        if (g != cur) {
            atomicAdd(&emb[(size_t)cur * HIDDEN + lane * 2], ax);
            atomicAdd(&emb[(size_t)cur * HIDDEN + lane * 2 + 1], ay);
            if (lane == 0) atomicAdd(&cnt[cur], run);
            cur = g; ax = 0.f; ay = 0.f; run = 0.f;
        }
        ushort2 u = *(const ushort2*)(h + (size_t)n * HIDDEN + lane * 2);
        ax += bf2f(u.x); ay += bf2f(u.y);
        run += 1.f;
    }
    atomicAdd(&emb[(size_t)cur * HIDDEN + lane * 2], ax);
    atomicAdd(&emb[(size_t)cur * HIDDEN + lane * 2 + 1], ay);
    if (lane == 0) atomicAdd(&cnt[cur], run);
}

__global__ __launch_bounds__(256) void mlp_kernel(const float* __restrict__ emb,
                                                  const float* __restrict__ cnt,
                                                  const float* __restrict__ fg,
                                                  const float* __restrict__ M1, const float* __restrict__ c1,
                                                  const float* __restrict__ M2, const float* __restrict__ c2,
                                                  const float* __restrict__ M3, const float* __restrict__ c3,
                                                  float* __restrict__ out) {
    const int g = blockIdx.x;
    const int t = threadIdx.x;
    __shared__ float z[HIDDEN + EXTRA];
    __shared__ float z1[2 * HIDDEN];
    __shared__ float z2[HIDDEN];
    if (t < HIDDEN) {
        float c = fmaxf(cnt[g], 1.f);
        z[t] = emb[(size_t)g * HIDDEN + t] / c;
    } else if (t < HIDDEN + EXTRA) {
        z[t] = fg[g * EXTRA + (t - HIDDEN)];
    }
    __syncthreads();
    {
        float s = c1[t];
        for (int k = 0; k < HIDDEN + EXTRA; ++k) s += z[k] * M1[k * (2 * HIDDEN) + t];
        z1[t] = selu_f(s);
    }
    __syncthreads();
    if (t < HIDDEN) {
        float s = c2[t];
        for (int k = 0; k < 2 * HIDDEN; ++k) s += z1[k] * M2[k * HIDDEN + t];
        z2[t] = selu_f(s);
    }
    __syncthreads();
    if (t < 64) {
        float s = z2[t] * M3[t] + z2[t + 64] * M3[t + 64];
#pragma unroll
        for (int off = 32; off; off >>= 1) s += __shfl_down(s, off);
        if (t == 0) out[g] = s + c3[0];
    }
}

extern "C" void kernel_launch(void* const* d_in, const int* in_sizes, int n_in,
                              void* d_out, int out_size, void* d_ws, size_t ws_size,
                              hipStream_t stream) {
    const float* feats_node  = (const float*)d_in[0];
    const float* feats_graph = (const float*)d_in[1];
    const int*   src         = (const int*)d_in[2];
    const int*   dst         = (const int*)d_in[3];
    const int*   gid         = (const int*)d_in[4];
    const float* W1 = (const float*)d_in[5];
    const float* b1 = (const float*)d_in[6];
    const float* W2 = (const float*)d_in[7];
    const float* b2 = (const float*)d_in[8];
    const float* W3 = (const float*)d_in[9];
    const float* b3 = (const float*)d_in[10];
    const float* M1 = (const float*)d_in[11];
    const float* c1 = (const float*)d_in[12];
    const float* M2 = (const float*)d_in[13];
    const float* c2 = (const float*)d_in[14];
    const float* M3 = (const float*)d_in[15];
    const float* c3 = (const float*)d_in[16];
    float* out = (float*)d_out;

    char* ws = (char*)d_ws;
    int* indeg   = (int*)ws;  ws += (size_t)N_NODES * sizeof(int);
    int* rowptr  = (int*)ws;  ws += (size_t)(N_NODES + 4) * sizeof(int);
    int* partials= (int*)ws;  ws += 512 * sizeof(int);
    float* norm_src = (float*)ws; ws += (size_t)N_NODES * sizeof(float);
    float* norm_dst = (float*)ws; ws += (size_t)N_NODES * sizeof(float);
    bf16_t* Wt1 = (bf16_t*)ws; ws += (size_t)128 * IN_FEATS * sizeof(bf16_t);
    bf16_t* Wt2 = (bf16_t*)ws; ws += (size_t)128 * HIDDEN * sizeof(bf16_t);
    bf16_t* Wt3 = (bf16_t*)ws; ws += (size_t)128 * HIDDEN * sizeof(bf16_t);
    int* csr_src = (int*)ws;  ws += (size_t)N_EDGES * sizeof(int);
    bf16_t* bufB = (bf16_t*)ws; ws += (size_t)N_NODES * HIDDEN * sizeof(bf16_t);
    // union 1: h_dst (alive histo..sortT) / bufA (alive after sortT)
    unsigned char* h_dst = (unsigned char*)ws;
    bf16_t* bufA = (bf16_t*)ws;
    ws += (size_t)G_SORT * N_NODES;                                  // 25.6 MB
    // union 2: h_src (alive histo..degs) / xb + emb + cnt
    unsigned char* h_src = (unsigned char*)ws;
    bf16_t* xb   = (bf16_t*)ws;
    float* emb   = (float*)(ws + (size_t)N_NODES * IN_FEATS * sizeof(bf16_t));
    float* cnt   = emb + (size_t)N_GRAPHS * HIDDEN;
    ws += (size_t)G_SORT * N_NODES;                                  // 25.6 MB

    // ---- CSR build (counting sort, no global atomics) ----
    histo_kernel<<<G_SORT, 512, 0, stream>>>(src, dst, h_src, h_dst);
    degs_kernel<<<(N_NODES + 255) / 256, 256, 0, stream>>>(h_src, h_dst, indeg, norm_src, norm_dst);
    scanA<<<NB_CHUNKS, 256, 0, stream>>>(indeg, partials);
    scanB<<<1, 128, 0, stream>>>(partials, rowptr);
    scanC<<<NB_CHUNKS, 256, 0, stream>>>(indeg, partials, rowptr);
    sortT_kernel<<<G_SORT, 512, 0, stream>>>(src, dst, h_dst, rowptr, csr_src);

    // ---- weight prep + prescale (xb overlays h_src: dead after degs) ----
    wprep_kernel<<<(128 * IN_FEATS + 255) / 256, 256, 0, stream>>>(W1, Wt1, IN_FEATS);
    wprep_kernel<<<(128 * HIDDEN + 255) / 256, 256, 0, stream>>>(W2, Wt2, HIDDEN);
    wprep_kernel<<<(128 * HIDDEN + 255) / 256, 256, 0, stream>>>(W3, Wt3, HIDDEN);
    prescale_kernel<<<(N_NODES * (IN_FEATS / 4) + 255) / 256, 256, 0, stream>>>(feats_node, norm_src, xb);

    const int mm_grid = (N_NODES + 63) / 64;
    const int g_grid  = (N_NODES + 3) / 4;   // 1 node/wave, 4 waves/block

    // layer 1: aggregate(64) -> MFMA matmul(64->128) w/ selu+bias+nsrc epilogue
    gather64_kernel<<<g_grid, 256, 0, stream>>>(xb, rowptr, csr_src, norm_dst, bufA);
    node_matmul_mfma<IN_FEATS, true><<<mm_grid, 256, 0, stream>>>(bufA, Wt1, b1, norm_src, bufB);

    // layer 2
    gather128_kernel<<<g_grid, 256, 0, stream>>>(bufB, rowptr, csr_src, norm_dst, bufA);
    node_matmul_mfma<HIDDEN, true><<<mm_grid, 256, 0, stream>>>(bufA, Wt2, b2, norm_src, bufB);

    // layer 3 (no nsrc on output; feeds pooling)
    gather128_kernel<<<g_grid, 256, 0, stream>>>(bufB, rowptr, csr_src, norm_dst, bufA);
    node_matmul_mfma<HIDDEN, false><<<mm_grid, 256, 0, stream>>>(bufA, Wt3, b3, norm_src, bufB);

    // readout + MLP (emb/cnt overlay xb tail region; xb dead after layer 1)
    hipMemsetAsync(emb, 0, ((size_t)N_GRAPHS * HIDDEN + N_GRAPHS) * sizeof(float), stream);
    const int n_waves = (N_NODES + 63) / 64;
    pool_kernel<<<(n_waves + 3) / 4, 256, 0, stream>>>(bufB, gid, emb, cnt);
    mlp_kernel<<<N_GRAPHS, 256, 0, stream>>>(emb, cnt, feats_graph,
                                             M1, c1, M2, c2, M3, c3, out);
}